// Round 9
// baseline (139.347 us; speedup 1.0000x reference)
//
#include <hip/hip_runtime.h>
#include <stdint.h>

typedef _Float16 half_t;
typedef _Float16 half8 __attribute__((ext_vector_type(8)));
typedef __fp16 fp16x2 __attribute__((ext_vector_type(2)));
typedef float floatx4 __attribute__((ext_vector_type(4)));
typedef float floatx16 __attribute__((ext_vector_type(16)));
typedef unsigned int uint;
typedef unsigned int uint4v __attribute__((ext_vector_type(4)));

#define LOG2E 1.4426950408889634f

__device__ __forceinline__ void gload_lds16(const void* g, void* l) {
  __builtin_amdgcn_global_load_lds(
      (__attribute__((address_space(1))) void*)(uintptr_t)g,
      (__attribute__((address_space(3))) void*)(uintptr_t)l, 16, 0, 0);
}

// involution swizzles: XOR byte bits 4..6 with low row bits (keeps 16B alignment)
__device__ __forceinline__ int swz64(int b)  { return b ^ (((b >> 7) & 3) << 4); }   // 64B rows
__device__ __forceinline__ int swz128(int b) { return b ^ (((b >> 7) & 7) << 4); }   // 128B rows

__device__ __forceinline__ uint pkrtz(float a, float b) {
  union { fp16x2 h; uint u; } cv;
  cv.h = __builtin_amdgcn_cvt_pkrtz(a, b);
  return cv.u;
}
__device__ __forceinline__ void pl32swap(uint &x, uint &y) {
  asm("v_permlane32_swap_b32 %0, %1" : "+v"(x), "+v"(y));
}
__device__ __forceinline__ half8 as_h8(uint4v v) {
  union { uint4v u; half8 h; } c; c.u = v; return c.h;
}

// ---------------- fp32 -> fp16 converts ----------------
__global__ void cvt_x_kernel(const float* __restrict__ X, half_t* __restrict__ X16) {
  int i = (blockIdx.x * 256 + threadIdx.x) * 8;
  float4 u = *(const float4*)(X + i);
  float4 v = *(const float4*)(X + i + 4);
  half8 o = {(half_t)u.x, (half_t)u.y, (half_t)u.z, (half_t)u.w,
             (half_t)v.x, (half_t)v.y, (half_t)v.z, (half_t)v.w};
  *(half8*)(X16 + i) = o;
}

__global__ void cvt_w_kernel(const float* __restrict__ Wq, const float* __restrict__ Wk,
                             const float* __restrict__ Wv, const float* __restrict__ Wo,
                             half_t* __restrict__ W16) {
  int i = blockIdx.x * 256 + threadIdx.x;
  int widx = i >> 15;
  int j = (i & 32767) * 8;
  const float* src = (widx == 0) ? Wq : (widx == 1) ? Wk : (widx == 2) ? Wv : Wo;
  float sc = (widx == 0) ? 0.125f * LOG2E : 1.0f;  // fold 1/sqrt(64) AND log2(e) into Wq
  float4 u = *(const float4*)(src + j);
  float4 v = *(const float4*)(src + j + 4);
  half8 o = {(half_t)(u.x * sc), (half_t)(u.y * sc), (half_t)(u.z * sc), (half_t)(u.w * sc),
             (half_t)(v.x * sc), (half_t)(v.y * sc), (half_t)(v.z * sc), (half_t)(v.w * sc)};
  *(half8*)(W16 + widx * 262144 + j) = o;
}

// ---------------- NT fp16 GEMM, 128x128 tile, BK=32, K=512 ----------------
template <int MODE>
__global__ __launch_bounds__(256) void gemm_nt(
    const half_t* __restrict__ A, const half_t* __restrict__ B0,
    const half_t* __restrict__ B1, half_t* __restrict__ outh,
    half_t* __restrict__ outh2, float* __restrict__ outf,
    const float* __restrict__ bias) {
  __shared__ __attribute__((aligned(16))) half_t As[128 * 32];
  __shared__ __attribute__((aligned(16))) half_t Bs[128 * 32];

  const int tid = threadIdx.x;
  const int w = tid >> 6, l = tid & 63, g = l >> 4, c = l & 15;
  const int wr = w >> 1, wc = w & 1;
  const int bidx = blockIdx.x;

  int rt, ct;
  const half_t *Ab, *Bb;
  if (MODE == 0) {
    rt = bidx >> 3; ct = bidx & 7;
    Ab = A + (size_t)rt * 128 * 512;
    Bb = ((ct < 4) ? B0 : B1) + (size_t)(ct & 3) * 128 * 512;
  } else if (MODE == 1) {
    rt = bidx >> 6; ct = bidx & 63;
    Ab = A + (size_t)rt * 128 * 512;
    Bb = B0 + (size_t)ct * 128 * 512;
  } else {
    rt = bidx >> 2; ct = bidx & 3;
    Ab = A + (size_t)rt * 128 * 512;
    Bb = B0 + (size_t)ct * 128 * 512;
  }

  const floatx4 fzero = {0.f, 0.f, 0.f, 0.f};
  floatx4 acc[4][4];
#pragma unroll
  for (int m = 0; m < 4; ++m)
#pragma unroll
    for (int n = 0; n < 4; ++n) acc[m][n] = fzero;

  for (int kt = 0; kt < 16; ++kt) {
    __syncthreads();
#pragma unroll
    for (int i = 0; i < 2; ++i) {
      int rel = i * 4096 + tid * 16;
      int lg = swz64(rel);
      int row = lg >> 6, inner = (lg & 63) >> 1;
      gload_lds16(Ab + (size_t)row * 512 + kt * 32 + inner, As + (rel >> 1));
      gload_lds16(Bb + (size_t)row * 512 + kt * 32 + inner, Bs + (rel >> 1));
    }
    __syncthreads();
    half8 a[4], b[4];
#pragma unroll
    for (int m = 0; m < 4; ++m)
      a[m] = *(const half8*)&As[swz64(((wr * 64 + m * 16 + c) << 6) + (g << 4)) >> 1];
#pragma unroll
    for (int n = 0; n < 4; ++n)
      b[n] = *(const half8*)&Bs[swz64(((wc * 64 + n * 16 + c) << 6) + (g << 4)) >> 1];
#pragma unroll
    for (int m = 0; m < 4; ++m)
#pragma unroll
      for (int n = 0; n < 4; ++n)
        acc[m][n] = __builtin_amdgcn_mfma_f32_16x16x32_f16(a[m], b[n], acc[m][n], 0, 0, 0);
  }

  const int r0 = wr * 64, c0 = wc * 64;
  if (MODE == 0) {
    half_t* O = ((ct < 4) ? outh : outh2) + (size_t)rt * 128 * 512 + (size_t)(ct & 3) * 128;
#pragma unroll
    for (int m = 0; m < 4; ++m)
#pragma unroll
      for (int j = 0; j < 4; ++j)
#pragma unroll
        for (int n = 0; n < 4; ++n)
          O[(size_t)(r0 + m * 16 + g * 4 + j) * 512 + c0 + n * 16 + c] = (half_t)acc[m][n][j];
  } else if (MODE == 1) {
    half_t* O = outh + (size_t)(ct >> 5) * 2097152 + (size_t)(ct & 31) * 128;
#pragma unroll
    for (int m = 0; m < 4; ++m)
#pragma unroll
      for (int j = 0; j < 4; ++j)
#pragma unroll
        for (int n = 0; n < 4; ++n)
          O[(size_t)(rt * 128 + r0 + m * 16 + g * 4 + j) * 4096 + c0 + n * 16 + c] =
              (half_t)acc[m][n][j];
  } else {
    float* O = outf + (size_t)rt * 128 * 512 + ct * 128;
    float bv[4];
#pragma unroll
    for (int n = 0; n < 4; ++n) bv[n] = bias[ct * 128 + c0 + n * 16 + c];
#pragma unroll
    for (int m = 0; m < 4; ++m)
#pragma unroll
      for (int j = 0; j < 4; ++j)
#pragma unroll
        for (int n = 0; n < 4; ++n)
          O[(size_t)(r0 + m * 16 + g * 4 + j) * 512 + c0 + n * 16 + c] = acc[m][n][j] + bv[n];
  }
}

// ---------------- flash attention v8 ----------------
// v6 (verified) inner code, 8 waves: the 4 (kw,qw) roles x tile-parity tp.
// tp=0 waves process even KV tiles, tp=1 odd tiles (independent acc/lf, merged
// at end). Grid 512 (unchanged), LDS 66KB -> 2 blocks/CU x 8 waves = 16 waves/CU.
// Barriers halve (32 rounds). Per-wave QK/pack/PV/epilogue math is v6 verbatim.
__global__ __launch_bounds__(512, 2) void attn_kernel(
    const half_t* __restrict__ Q16, const half_t* __restrict__ K16,
    const half_t* __restrict__ Vt, half_t* __restrict__ O16) {
  // [0,32K): K slots [pair][tp][4096 halves]; [32K,64K): V slots; [64K,66K): redl
  __shared__ __attribute__((aligned(16))) char smem[67584];
  half_t* kb_lds = (half_t*)smem;
  half_t* vb_lds = (half_t*)(smem + 32768);

  const int tid = threadIdx.x;
  const int w = tid >> 6, l = tid & 63, lo = l & 31, h = l >> 5;
  const int tp = w >> 2, w4 = w & 3;
  const int kw = w4 >> 1, qw = w4 & 1;
  // bijective XCD swizzle: 512 blocks -> chunks of 64 per XCD (as v6)
  const int bid = (blockIdx.x & 7) * 64 + (blockIdx.x >> 3);
  const int bh = bid >> 5, qt = bid & 31;
  const int b = bh >> 3, hh = bh & 7;

  const half_t* Qb = Q16 + (size_t)(b * 4096 + qt * 128 + qw * 64) * 512 + hh * 64;
  const half_t* Kb = K16 + (size_t)b * 4096 * 512 + hh * 64;
  const half_t* Vb = Vt + (size_t)bh * 262144;  // [64 d][4096 s]
  half_t* Ob = O16 + (size_t)(b * 4096 + qt * 128 + qw * 64) * 512 + hh * 64;

  // Q fragments (B-operand): row q = qm*32+lo, elems d = ks*16 + h*8 .. +7
  half8 qa[2][4];
#pragma unroll
  for (int qm = 0; qm < 2; ++qm)
#pragma unroll
    for (int ks = 0; ks < 4; ++ks)
      qa[qm][ks] = *(const half8*)(Qb + (size_t)(qm * 32 + lo) * 512 + ks * 16 + h * 8);

  floatx16 acc[2][2];
#pragma unroll
  for (int qm = 0; qm < 2; ++qm)
#pragma unroll
    for (int dn = 0; dn < 2; ++dn)
#pragma unroll
      for (int r = 0; r < 16; ++r) acc[qm][dn][r] = 0.f;
  float lf[2] = {0.f, 0.f};

  // stage tiles t0 (slot 0) and t0+1 (slot 1) into pair; 512 thr cover 8KB/tile
  auto stage2 = [&](int pair, int t0) {
    int rel = tid * 16;  // [0,8192)
    int lg = swz128(rel);
    int row = lg >> 7, inner = (lg & 127) >> 1;
#pragma unroll
    for (int sl = 0; sl < 2; ++sl) {
      gload_lds16(Kb + (size_t)((t0 + sl) * 64 + row) * 512 + inner,
                  kb_lds + pair * 8192 + sl * 4096 + (rel >> 1));
      gload_lds16(Vb + (size_t)row * 4096 + (t0 + sl) * 64 + inner,
                  vb_lds + pair * 8192 + sl * 4096 + (rel >> 1));
    }
  };

  stage2(0, 0);

  for (int j = 0; j < 32; ++j) {
    __syncthreads();  // staging of pair (j&1) drained; prev reads of (j+1)&1 done
    if (j < 31) stage2((j + 1) & 1, 2 * (j + 1));
    const half_t* kt = kb_lds + (j & 1) * 8192 + tp * 4096;
    const half_t* vt = vb_lds + (j & 1) * 8192 + tp * 4096;

    // S^T[key][q] = K.Q^T; wave covers keys kw*32..+32 of tile 2j+tp, q qw*64..+64
    floatx16 s[2];  // [qm]
#pragma unroll
    for (int qm = 0; qm < 2; ++qm)
#pragma unroll
      for (int r = 0; r < 16; ++r) s[qm][r] = 0.f;

#pragma unroll
    for (int ks = 0; ks < 4; ++ks) {
      int byte = ((kw * 32 + lo) << 7) + (ks << 5) + (h << 4);
      half8 ka = *(const half8*)&kt[swz128(byte) >> 1];
#pragma unroll
      for (int qm = 0; qm < 2; ++qm)
        s[qm] = __builtin_amdgcn_mfma_f32_32x32x16_f16(ka, qa[qm][ks], s[qm], 0, 0, 0);
    }

    // P = exp2(S^T) in-place; in-lane row partial sums; pack to PV A-frags (T12)
    uint4v pa[2][2];
#pragma unroll
    for (int qm = 0; qm < 2; ++qm) {
      float psum = 0.f;
#pragma unroll
      for (int r = 0; r < 16; ++r) {
        float e = __builtin_amdgcn_exp2f(s[qm][r]);
        s[qm][r] = e;
        psum += e;
      }
      lf[qm] += psum;
#pragma unroll
      for (int ksb = 0; ksb < 2; ++ksb) {
        uint x0 = pkrtz(s[qm][8 * ksb + 0], s[qm][8 * ksb + 1]);
        uint x1 = pkrtz(s[qm][8 * ksb + 2], s[qm][8 * ksb + 3]);
        uint y0 = pkrtz(s[qm][8 * ksb + 4], s[qm][8 * ksb + 5]);
        uint y1 = pkrtz(s[qm][8 * ksb + 6], s[qm][8 * ksb + 7]);
        pl32swap(x0, y0);
        pl32swap(x1, y1);
        pa[qm][ksb] = (uint4v){x0, x1, y0, y1};
      }
    }

    // O += P V : A = pa (q rows x 16k), B = V^T rows (d rows x 16k keys)
#pragma unroll
    for (int dn = 0; dn < 2; ++dn)
#pragma unroll
      for (int ks = 0; ks < 2; ++ks) {
        int byte = ((dn * 32 + lo) << 7) + ((kw * 32 + ks * 16 + h * 8) << 1);
        half8 vb = *(const half8*)&vt[swz128(byte) >> 1];
#pragma unroll
        for (int qm = 0; qm < 2; ++qm)
          acc[qm][dn] =
              __builtin_amdgcn_mfma_f32_32x32x16_f16(as_h8(pa[qm][ks]), vb, acc[qm][dn], 0, 0, 0);
      }
  }

  // ---- tp merge: tp1 -> tp0, split into two qm rounds (32KB LDS each) ----
  float* red = (float*)smem;              // 32 KB (reuses K slots)
  float* redl = (float*)(smem + 65536);   // 2 KB

#pragma unroll
  for (int qm = 0; qm < 2; ++qm) {
    __syncthreads();
    if (tp == 1) {
      redl[qm * 256 + w4 * 64 + l] = lf[qm];
#pragma unroll
      for (int dn = 0; dn < 2; ++dn)
#pragma unroll
        for (int r = 0; r < 16; ++r)
          red[((w4 * 2 + dn) * 16 + r) * 64 + l] = acc[qm][dn][r];
    }
    __syncthreads();
    if (tp == 0) {
      lf[qm] += redl[qm * 256 + w4 * 64 + l];
#pragma unroll
      for (int dn = 0; dn < 2; ++dn)
#pragma unroll
        for (int r = 0; r < 16; ++r)
          acc[qm][dn][r] += red[((w4 * 2 + dn) * 16 + r) * 64 + l];
    }
  }

  // ---- v6 epilogue verbatim among tp==0 waves ----
#pragma unroll
  for (int qm = 0; qm < 2; ++qm) lf[qm] += __shfl_xor(lf[qm], 32);

  __syncthreads();
  if (tp == 0 && kw == 1) {
#pragma unroll
    for (int qm = 0; qm < 2; ++qm) {
      redl[(qw * 2 + qm) * 64 + l] = lf[qm];
#pragma unroll
      for (int dn = 0; dn < 2; ++dn)
#pragma unroll
        for (int r = 0; r < 16; ++r)
          red[((((qw * 2 + qm) * 2 + dn) * 16) + r) * 64 + l] = acc[qm][dn][r];
    }
  }
  __syncthreads();
  if (tp == 0 && kw == 0) {
    float inv[2];
#pragma unroll
    for (int qm = 0; qm < 2; ++qm)
      inv[qm] = 1.0f / (lf[qm] + redl[(qw * 2 + qm) * 64 + l]);
#pragma unroll
    for (int qm = 0; qm < 2; ++qm)
#pragma unroll
      for (int r = 0; r < 16; ++r) {
        int ro = (r & 3) + 8 * (r >> 2) + 4 * h;
        float iv = __shfl(inv[qm], ro);
#pragma unroll
        for (int dn = 0; dn < 2; ++dn) {
          float o = (acc[qm][dn][r] + red[((((qw * 2 + qm) * 2 + dn) * 16) + r) * 64 + l]) * iv;
          Ob[(size_t)(qm * 32 + ro) * 512 + dn * 32 + lo] = (half_t)o;
        }
      }
  }
}

extern "C" void kernel_launch(void* const* d_in, const int* in_sizes, int n_in,
                              void* d_out, int out_size, void* d_ws, size_t ws_size,
                              hipStream_t stream) {
  const float* X  = (const float*)d_in[0];
  const float* Wq = (const float*)d_in[1];
  const float* Wk = (const float*)d_in[2];
  const float* Wv = (const float*)d_in[3];
  const float* Wo = (const float*)d_in[4];
  const float* bo = (const float*)d_in[5];
  float* out = (float*)d_out;

  char* ws = (char*)d_ws;
  half_t* X16  = (half_t*)(ws);                 // 8 MB
  half_t* W16  = (half_t*)(ws + 8388608);       // 2 MB (Wq|Wk|Wv|Wo)
  half_t* Q16  = (half_t*)(ws + 10485760);      // 8 MB
  half_t* K16  = (half_t*)(ws + 18874368);      // 8 MB
  half_t* VtW  = (half_t*)(ws + 27262976);      // 8 MB  [B][H][64][4096]
  half_t* O16  = (half_t*)(ws + 35651584);      // 8 MB
  half_t* Wq16 = W16;
  half_t* Wk16 = W16 + 262144;
  half_t* Wv16 = W16 + 524288;
  half_t* Wo16 = W16 + 786432;

  cvt_x_kernel<<<2048, 256, 0, stream>>>(X, X16);
  cvt_w_kernel<<<512, 256, 0, stream>>>(Wq, Wk, Wv, Wo, W16);
  gemm_nt<0><<<512, 256, 0, stream>>>(X16, Wq16, Wk16, Q16, K16, nullptr, nullptr);
  gemm_nt<1><<<256, 256, 0, stream>>>(Wv16, X16, nullptr, VtW, nullptr, nullptr, nullptr);
  attn_kernel<<<512, 512, 0, stream>>>(Q16, K16, VtW, O16);
  gemm_nt<2><<<256, 256, 0, stream>>>(O16, Wo16, nullptr, nullptr, nullptr, out, bo);
}

// Round 10
// 137.736 us; speedup vs baseline: 1.0117x; 1.0117x over previous
//
#include <hip/hip_runtime.h>
#include <stdint.h>

typedef _Float16 half_t;
typedef _Float16 half8 __attribute__((ext_vector_type(8)));
typedef __fp16 fp16x2 __attribute__((ext_vector_type(2)));
typedef float floatx4 __attribute__((ext_vector_type(4)));
typedef float floatx16 __attribute__((ext_vector_type(16)));
typedef unsigned int uint;
typedef unsigned int uint4v __attribute__((ext_vector_type(4)));

#define LOG2E 1.4426950408889634f

__device__ __forceinline__ void gload_lds16(const void* g, void* l) {
  __builtin_amdgcn_global_load_lds(
      (__attribute__((address_space(1))) void*)(uintptr_t)g,
      (__attribute__((address_space(3))) void*)(uintptr_t)l, 16, 0, 0);
}

// involution swizzles: XOR byte bits 4..6 with low row bits (keeps 16B alignment)
__device__ __forceinline__ int swz64(int b)  { return b ^ (((b >> 7) & 3) << 4); }   // 64B rows
__device__ __forceinline__ int swz128(int b) { return b ^ (((b >> 7) & 7) << 4); }   // 128B rows

__device__ __forceinline__ uint pkrtz(float a, float b) {
  union { fp16x2 h; uint u; } cv;
  cv.h = __builtin_amdgcn_cvt_pkrtz(a, b);
  return cv.u;
}
__device__ __forceinline__ void pl32swap(uint &x, uint &y) {
  asm("v_permlane32_swap_b32 %0, %1" : "+v"(x), "+v"(y));
}
__device__ __forceinline__ half8 as_h8(uint4v v) {
  union { uint4v u; half8 h; } c; c.u = v; return c.h;
}

// ---------------- fp32 -> fp16 converts ----------------
__global__ void cvt_x_kernel(const float* __restrict__ X, half_t* __restrict__ X16) {
  int i = (blockIdx.x * 256 + threadIdx.x) * 8;
  float4 u = *(const float4*)(X + i);
  float4 v = *(const float4*)(X + i + 4);
  half8 o = {(half_t)u.x, (half_t)u.y, (half_t)u.z, (half_t)u.w,
             (half_t)v.x, (half_t)v.y, (half_t)v.z, (half_t)v.w};
  *(half8*)(X16 + i) = o;
}

__global__ void cvt_w_kernel(const float* __restrict__ Wq, const float* __restrict__ Wk,
                             const float* __restrict__ Wv, const float* __restrict__ Wo,
                             half_t* __restrict__ W16) {
  int i = blockIdx.x * 256 + threadIdx.x;
  int widx = i >> 15;
  int j = (i & 32767) * 8;
  const float* src = (widx == 0) ? Wq : (widx == 1) ? Wk : (widx == 2) ? Wv : Wo;
  float sc = (widx == 0) ? 0.125f * LOG2E : 1.0f;  // fold 1/sqrt(64) AND log2(e) into Wq
  float4 u = *(const float4*)(src + j);
  float4 v = *(const float4*)(src + j + 4);
  half8 o = {(half_t)(u.x * sc), (half_t)(u.y * sc), (half_t)(u.z * sc), (half_t)(u.w * sc),
             (half_t)(v.x * sc), (half_t)(v.y * sc), (half_t)(v.z * sc), (half_t)(v.w * sc)};
  *(half8*)(W16 + widx * 262144 + j) = o;
}

// ---------------- NT fp16 GEMM, 128x128 tile, BK=32, K=512 ----------------
template <int MODE>
__global__ __launch_bounds__(256) void gemm_nt(
    const half_t* __restrict__ A, const half_t* __restrict__ B0,
    const half_t* __restrict__ B1, half_t* __restrict__ outh,
    half_t* __restrict__ outh2, float* __restrict__ outf,
    const float* __restrict__ bias) {
  __shared__ __attribute__((aligned(16))) half_t As[128 * 32];
  __shared__ __attribute__((aligned(16))) half_t Bs[128 * 32];

  const int tid = threadIdx.x;
  const int w = tid >> 6, l = tid & 63, g = l >> 4, c = l & 15;
  const int wr = w >> 1, wc = w & 1;
  const int bidx = blockIdx.x;

  int rt, ct;
  const half_t *Ab, *Bb;
  if (MODE == 0) {
    rt = bidx >> 3; ct = bidx & 7;
    Ab = A + (size_t)rt * 128 * 512;
    Bb = ((ct < 4) ? B0 : B1) + (size_t)(ct & 3) * 128 * 512;
  } else if (MODE == 1) {
    rt = bidx >> 6; ct = bidx & 63;
    Ab = A + (size_t)rt * 128 * 512;
    Bb = B0 + (size_t)ct * 128 * 512;
  } else {
    rt = bidx >> 2; ct = bidx & 3;
    Ab = A + (size_t)rt * 128 * 512;
    Bb = B0 + (size_t)ct * 128 * 512;
  }

  const floatx4 fzero = {0.f, 0.f, 0.f, 0.f};
  floatx4 acc[4][4];
#pragma unroll
  for (int m = 0; m < 4; ++m)
#pragma unroll
    for (int n = 0; n < 4; ++n) acc[m][n] = fzero;

  for (int kt = 0; kt < 16; ++kt) {
    __syncthreads();
#pragma unroll
    for (int i = 0; i < 2; ++i) {
      int rel = i * 4096 + tid * 16;
      int lg = swz64(rel);
      int row = lg >> 6, inner = (lg & 63) >> 1;
      gload_lds16(Ab + (size_t)row * 512 + kt * 32 + inner, As + (rel >> 1));
      gload_lds16(Bb + (size_t)row * 512 + kt * 32 + inner, Bs + (rel >> 1));
    }
    __syncthreads();
    half8 a[4], b[4];
#pragma unroll
    for (int m = 0; m < 4; ++m)
      a[m] = *(const half8*)&As[swz64(((wr * 64 + m * 16 + c) << 6) + (g << 4)) >> 1];
#pragma unroll
    for (int n = 0; n < 4; ++n)
      b[n] = *(const half8*)&Bs[swz64(((wc * 64 + n * 16 + c) << 6) + (g << 4)) >> 1];
#pragma unroll
    for (int m = 0; m < 4; ++m)
#pragma unroll
      for (int n = 0; n < 4; ++n)
        acc[m][n] = __builtin_amdgcn_mfma_f32_16x16x32_f16(a[m], b[n], acc[m][n], 0, 0, 0);
  }

  const int r0 = wr * 64, c0 = wc * 64;
  if (MODE == 0) {
    half_t* O = ((ct < 4) ? outh : outh2) + (size_t)rt * 128 * 512 + (size_t)(ct & 3) * 128;
#pragma unroll
    for (int m = 0; m < 4; ++m)
#pragma unroll
      for (int j = 0; j < 4; ++j)
#pragma unroll
        for (int n = 0; n < 4; ++n)
          O[(size_t)(r0 + m * 16 + g * 4 + j) * 512 + c0 + n * 16 + c] = (half_t)acc[m][n][j];
  } else if (MODE == 1) {
    half_t* O = outh + (size_t)(ct >> 5) * 2097152 + (size_t)(ct & 31) * 128;
#pragma unroll
    for (int m = 0; m < 4; ++m)
#pragma unroll
      for (int j = 0; j < 4; ++j)
#pragma unroll
        for (int n = 0; n < 4; ++n)
          O[(size_t)(rt * 128 + r0 + m * 16 + g * 4 + j) * 4096 + c0 + n * 16 + c] =
              (half_t)acc[m][n][j];
  } else {
    float* O = outf + (size_t)rt * 128 * 512 + ct * 128;
    float bv[4];
#pragma unroll
    for (int n = 0; n < 4; ++n) bv[n] = bias[ct * 128 + c0 + n * 16 + c];
#pragma unroll
    for (int m = 0; m < 4; ++m)
#pragma unroll
      for (int j = 0; j < 4; ++j)
#pragma unroll
        for (int n = 0; n < 4; ++n)
          O[(size_t)(r0 + m * 16 + g * 4 + j) * 512 + c0 + n * 16 + c] = acc[m][n][j] + bv[n];
  }
}

// ---------------- flash attention v9 ----------------
// v6 (verified, absmax 8.5e-4) with the T4 lever: 4-deep K/V slot ring,
// counted s_waitcnt vmcnt(8) + raw s_barrier per round (never drain to 0 in
// the main loop), stage(t+3) issued before compute. T5 setprio around MFMA.
// All fragment/stage/epilogue math byte-identical to v6.
__global__ __launch_bounds__(256, 2) void attn_kernel(
    const half_t* __restrict__ Q16, const half_t* __restrict__ K16,
    const half_t* __restrict__ Vt, half_t* __restrict__ O16) {
  // [0,32K): K slots [4][64 key][64 d]; [32K,64K): V slots [4][64 d][64 key];
  // [64K,65K): redl. Epilogue red reuses [0,32K).
  __shared__ __attribute__((aligned(16))) char smem[66560];
  half_t* kb_lds = (half_t*)smem;
  half_t* vb_lds = (half_t*)(smem + 32768);

  const int tid = threadIdx.x;
  const int w = tid >> 6, l = tid & 63, lo = l & 31, h = l >> 5;
  const int kw = w >> 1, qw = w & 1;
  // bijective XCD swizzle: 512 blocks -> chunks of 64 per XCD
  const int bid = (blockIdx.x & 7) * 64 + (blockIdx.x >> 3);
  const int bh = bid >> 5, qt = bid & 31;
  const int b = bh >> 3, hh = bh & 7;

  const half_t* Qb = Q16 + (size_t)(b * 4096 + qt * 128 + qw * 64) * 512 + hh * 64;
  const half_t* Kb = K16 + (size_t)b * 4096 * 512 + hh * 64;
  const half_t* Vb = Vt + (size_t)bh * 262144;  // [64 d][4096 s]
  half_t* Ob = O16 + (size_t)(b * 4096 + qt * 128 + qw * 64) * 512 + hh * 64;

  // Q fragments (B-operand): row q = qm*32+lo, elems d = ks*16 + h*8 .. +7
  half8 qa[2][4];
#pragma unroll
  for (int qm = 0; qm < 2; ++qm)
#pragma unroll
    for (int ks = 0; ks < 4; ++ks)
      qa[qm][ks] = *(const half8*)(Qb + (size_t)(qm * 32 + lo) * 512 + ks * 16 + h * 8);

  floatx16 acc[2][2];
#pragma unroll
  for (int qm = 0; qm < 2; ++qm)
#pragma unroll
    for (int dn = 0; dn < 2; ++dn)
#pragma unroll
      for (int r = 0; r < 16; ++r) acc[qm][dn][r] = 0.f;
  float lf[2] = {0.f, 0.f};

  // stage K/V tile t (64 keys) into slot; linear LDS dest, pre-swizzled src.
  // 4 gload_lds per thread per stage.
  auto stage = [&](int slot, int t) {
#pragma unroll
    for (int i = 0; i < 2; ++i) {
      int rel = i * 4096 + tid * 16;
      int lg = swz128(rel);
      int row = lg >> 7, inner = (lg & 127) >> 1;
      gload_lds16(Kb + (size_t)(t * 64 + row) * 512 + inner,
                  kb_lds + slot * 4096 + (rel >> 1));
      gload_lds16(Vb + (size_t)row * 4096 + t * 64 + inner,
                  vb_lds + slot * 4096 + (rel >> 1));
    }
  };

  // compute one 64-key tile from a slot (v6 body verbatim, + setprio)
  auto compute = [&](int slot) {
    const half_t* kt = kb_lds + slot * 4096;
    const half_t* vt = vb_lds + slot * 4096;

    floatx16 s[2];  // [qm]
#pragma unroll
    for (int qm = 0; qm < 2; ++qm)
#pragma unroll
      for (int r = 0; r < 16; ++r) s[qm][r] = 0.f;

    __builtin_amdgcn_s_setprio(1);
#pragma unroll
    for (int ks = 0; ks < 4; ++ks) {
      int byte = ((kw * 32 + lo) << 7) + (ks << 5) + (h << 4);
      half8 ka = *(const half8*)&kt[swz128(byte) >> 1];
#pragma unroll
      for (int qm = 0; qm < 2; ++qm)
        s[qm] = __builtin_amdgcn_mfma_f32_32x32x16_f16(ka, qa[qm][ks], s[qm], 0, 0, 0);
    }
    __builtin_amdgcn_s_setprio(0);

    // P = exp2(S^T) in-place; in-lane row partial sums; pack to PV A-frags (T12)
    uint4v pa[2][2];
#pragma unroll
    for (int qm = 0; qm < 2; ++qm) {
      float psum = 0.f;
#pragma unroll
      for (int r = 0; r < 16; ++r) {
        float e = __builtin_amdgcn_exp2f(s[qm][r]);
        s[qm][r] = e;
        psum += e;
      }
      lf[qm] += psum;
#pragma unroll
      for (int ksb = 0; ksb < 2; ++ksb) {
        uint x0 = pkrtz(s[qm][8 * ksb + 0], s[qm][8 * ksb + 1]);
        uint x1 = pkrtz(s[qm][8 * ksb + 2], s[qm][8 * ksb + 3]);
        uint y0 = pkrtz(s[qm][8 * ksb + 4], s[qm][8 * ksb + 5]);
        uint y1 = pkrtz(s[qm][8 * ksb + 6], s[qm][8 * ksb + 7]);
        pl32swap(x0, y0);
        pl32swap(x1, y1);
        pa[qm][ksb] = (uint4v){x0, x1, y0, y1};
      }
    }

    // O += P V : A = pa (q rows x 16k), B = V^T rows (d rows x 16k keys)
    __builtin_amdgcn_s_setprio(1);
#pragma unroll
    for (int dn = 0; dn < 2; ++dn)
#pragma unroll
      for (int ks = 0; ks < 2; ++ks) {
        int byte = ((dn * 32 + lo) << 7) + ((kw * 32 + ks * 16 + h * 8) << 1);
        half8 vb = *(const half8*)&vt[swz128(byte) >> 1];
#pragma unroll
        for (int qm = 0; qm < 2; ++qm)
          acc[qm][dn] =
              __builtin_amdgcn_mfma_f32_32x32x16_f16(as_h8(pa[qm][ks]), vb, acc[qm][dn], 0, 0, 0);
      }
    __builtin_amdgcn_s_setprio(0);
  };

  // prologue: 3 tiles in flight (12 outstanding gload_lds per thread)
  stage(0, 0);
  stage(1, 1);
  stage(2, 2);

  // main loop: counted vmcnt (oldest stage drained, 2 stages stay in flight)
  for (int t = 0; t < 61; ++t) {
    asm volatile("s_waitcnt vmcnt(8)" ::: "memory");
    __builtin_amdgcn_s_barrier();
    __builtin_amdgcn_sched_barrier(0);
    stage((t + 3) & 3, t + 3);  // overwrites slot read at t-1 (reads consumed)
    compute(t & 3);
  }
  // tail: t=61 (12 in flight), t=62 (8), t=63 (4)
  asm volatile("s_waitcnt vmcnt(8)" ::: "memory");
  __builtin_amdgcn_s_barrier();
  __builtin_amdgcn_sched_barrier(0);
  compute(1);
  asm volatile("s_waitcnt vmcnt(4)" ::: "memory");
  __builtin_amdgcn_s_barrier();
  __builtin_amdgcn_sched_barrier(0);
  compute(2);
  asm volatile("s_waitcnt vmcnt(0)" ::: "memory");
  __builtin_amdgcn_s_barrier();
  __builtin_amdgcn_sched_barrier(0);
  compute(3);

  // ---- cross-wave (k-half) reduction + normalize + store (v6 verbatim) ----
#pragma unroll
  for (int qm = 0; qm < 2; ++qm) lf[qm] += __shfl_xor(lf[qm], 32);

  float* red = (float*)smem;             // 32 KB: [qw][qm][dn][r][lane]
  float* redl = (float*)(smem + 65536);  // 1 KB: [qw][qm][lane]

  __syncthreads();
  if (kw == 1) {
#pragma unroll
    for (int qm = 0; qm < 2; ++qm) {
      redl[(qw * 2 + qm) * 64 + l] = lf[qm];
#pragma unroll
      for (int dn = 0; dn < 2; ++dn)
#pragma unroll
        for (int r = 0; r < 16; ++r)
          red[((((qw * 2 + qm) * 2 + dn) * 16) + r) * 64 + l] = acc[qm][dn][r];
    }
  }
  __syncthreads();
  if (kw == 0) {
    float inv[2];
#pragma unroll
    for (int qm = 0; qm < 2; ++qm)
      inv[qm] = 1.0f / (lf[qm] + redl[(qw * 2 + qm) * 64 + l]);
#pragma unroll
    for (int qm = 0; qm < 2; ++qm)
#pragma unroll
      for (int r = 0; r < 16; ++r) {
        int ro = (r & 3) + 8 * (r >> 2) + 4 * h;
        float iv = __shfl(inv[qm], ro);
#pragma unroll
        for (int dn = 0; dn < 2; ++dn) {
          float o = (acc[qm][dn][r] + red[((((qw * 2 + qm) * 2 + dn) * 16) + r) * 64 + l]) * iv;
          Ob[(size_t)(qm * 32 + ro) * 512 + dn * 32 + lo] = (half_t)o;
        }
      }
  }
}

extern "C" void kernel_launch(void* const* d_in, const int* in_sizes, int n_in,
                              void* d_out, int out_size, void* d_ws, size_t ws_size,
                              hipStream_t stream) {
  const float* X  = (const float*)d_in[0];
  const float* Wq = (const float*)d_in[1];
  const float* Wk = (const float*)d_in[2];
  const float* Wv = (const float*)d_in[3];
  const float* Wo = (const float*)d_in[4];
  const float* bo = (const float*)d_in[5];
  float* out = (float*)d_out;

  char* ws = (char*)d_ws;
  half_t* X16  = (half_t*)(ws);                 // 8 MB
  half_t* W16  = (half_t*)(ws + 8388608);       // 2 MB (Wq|Wk|Wv|Wo)
  half_t* Q16  = (half_t*)(ws + 10485760);      // 8 MB
  half_t* K16  = (half_t*)(ws + 18874368);      // 8 MB
  half_t* VtW  = (half_t*)(ws + 27262976);      // 8 MB  [B][H][64][4096]
  half_t* O16  = (half_t*)(ws + 35651584);      // 8 MB
  half_t* Wq16 = W16;
  half_t* Wk16 = W16 + 262144;
  half_t* Wv16 = W16 + 524288;
  half_t* Wo16 = W16 + 786432;

  cvt_x_kernel<<<2048, 256, 0, stream>>>(X, X16);
  cvt_w_kernel<<<512, 256, 0, stream>>>(Wq, Wk, Wv, Wo, W16);
  gemm_nt<0><<<512, 256, 0, stream>>>(X16, Wq16, Wk16, Q16, K16, nullptr, nullptr);
  gemm_nt<1><<<256, 256, 0, stream>>>(Wv16, X16, nullptr, VtW, nullptr, nullptr, nullptr);
  attn_kernel<<<512, 256, 0, stream>>>(Q16, K16, VtW, O16);
  gemm_nt<2><<<256, 256, 0, stream>>>(O16, Wo16, nullptr, nullptr, nullptr, out, bo);
}

// Round 11
// 134.156 us; speedup vs baseline: 1.0387x; 1.0267x over previous
//
#include <hip/hip_runtime.h>
#include <stdint.h>

typedef _Float16 half_t;
typedef _Float16 half8 __attribute__((ext_vector_type(8)));
typedef __fp16 fp16x2 __attribute__((ext_vector_type(2)));
typedef float floatx4 __attribute__((ext_vector_type(4)));
typedef float floatx16 __attribute__((ext_vector_type(16)));
typedef unsigned int uint;
typedef unsigned int uint4v __attribute__((ext_vector_type(4)));

#define LOG2E 1.4426950408889634f

__device__ __forceinline__ void gload_lds16(const void* g, void* l) {
  __builtin_amdgcn_global_load_lds(
      (__attribute__((address_space(1))) void*)(uintptr_t)g,
      (__attribute__((address_space(3))) void*)(uintptr_t)l, 16, 0, 0);
}

// involution swizzles: XOR byte bits 4..6 with low row bits (keeps 16B alignment)
__device__ __forceinline__ int swz64(int b)  { return b ^ (((b >> 7) & 3) << 4); }   // 64B rows
__device__ __forceinline__ int swz128(int b) { return b ^ (((b >> 7) & 7) << 4); }   // 128B rows

__device__ __forceinline__ uint pkrtz(float a, float b) {
  union { fp16x2 h; uint u; } cv;
  cv.h = __builtin_amdgcn_cvt_pkrtz(a, b);
  return cv.u;
}
__device__ __forceinline__ void pl32swap(uint &x, uint &y) {
  asm("v_permlane32_swap_b32 %0, %1" : "+v"(x), "+v"(y));
}
__device__ __forceinline__ half8 as_h8(uint4v v) {
  union { uint4v u; half8 h; } c; c.u = v; return c.h;
}

#define WAITB(N)                                          \
  asm volatile("s_waitcnt vmcnt(" #N ")" ::: "memory");   \
  __builtin_amdgcn_s_barrier();                           \
  __builtin_amdgcn_sched_barrier(0);

// ---------------- fp32 -> fp16 converts ----------------
__global__ void cvt_x_kernel(const float* __restrict__ X, half_t* __restrict__ X16) {
  int i = (blockIdx.x * 256 + threadIdx.x) * 8;
  float4 u = *(const float4*)(X + i);
  float4 v = *(const float4*)(X + i + 4);
  half8 o = {(half_t)u.x, (half_t)u.y, (half_t)u.z, (half_t)u.w,
             (half_t)v.x, (half_t)v.y, (half_t)v.z, (half_t)v.w};
  *(half8*)(X16 + i) = o;
}

__global__ void cvt_w_kernel(const float* __restrict__ Wq, const float* __restrict__ Wk,
                             const float* __restrict__ Wv, const float* __restrict__ Wo,
                             half_t* __restrict__ W16) {
  int i = blockIdx.x * 256 + threadIdx.x;
  int widx = i >> 15;
  int j = (i & 32767) * 8;
  const float* src = (widx == 0) ? Wq : (widx == 1) ? Wk : (widx == 2) ? Wv : Wo;
  float sc = (widx == 0) ? 0.125f * LOG2E : 1.0f;  // fold 1/sqrt(64) AND log2(e) into Wq
  float4 u = *(const float4*)(src + j);
  float4 v = *(const float4*)(src + j + 4);
  half8 o = {(half_t)(u.x * sc), (half_t)(u.y * sc), (half_t)(u.z * sc), (half_t)(u.w * sc),
             (half_t)(v.x * sc), (half_t)(v.y * sc), (half_t)(v.z * sc), (half_t)(v.w * sc)};
  *(half8*)(W16 + widx * 262144 + j) = o;
}

// ---------------- NT fp16 GEMM, 128x128 tile, BK=32, K=512 ----------------
template <int MODE>
__global__ __launch_bounds__(256) void gemm_nt(
    const half_t* __restrict__ A, const half_t* __restrict__ B0,
    const half_t* __restrict__ B1, half_t* __restrict__ outh,
    half_t* __restrict__ outh2, float* __restrict__ outf,
    const float* __restrict__ bias) {
  __shared__ __attribute__((aligned(16))) half_t As[128 * 32];
  __shared__ __attribute__((aligned(16))) half_t Bs[128 * 32];

  const int tid = threadIdx.x;
  const int w = tid >> 6, l = tid & 63, g = l >> 4, c = l & 15;
  const int wr = w >> 1, wc = w & 1;
  const int bidx = blockIdx.x;

  int rt, ct;
  const half_t *Ab, *Bb;
  if (MODE == 0) {
    rt = bidx >> 3; ct = bidx & 7;
    Ab = A + (size_t)rt * 128 * 512;
    Bb = ((ct < 4) ? B0 : B1) + (size_t)(ct & 3) * 128 * 512;
  } else if (MODE == 1) {
    rt = bidx >> 6; ct = bidx & 63;
    Ab = A + (size_t)rt * 128 * 512;
    Bb = B0 + (size_t)ct * 128 * 512;
  } else {
    rt = bidx >> 2; ct = bidx & 3;
    Ab = A + (size_t)rt * 128 * 512;
    Bb = B0 + (size_t)ct * 128 * 512;
  }

  const floatx4 fzero = {0.f, 0.f, 0.f, 0.f};
  floatx4 acc[4][4];
#pragma unroll
  for (int m = 0; m < 4; ++m)
#pragma unroll
    for (int n = 0; n < 4; ++n) acc[m][n] = fzero;

  for (int kt = 0; kt < 16; ++kt) {
    __syncthreads();
#pragma unroll
    for (int i = 0; i < 2; ++i) {
      int rel = i * 4096 + tid * 16;
      int lg = swz64(rel);
      int row = lg >> 6, inner = (lg & 63) >> 1;
      gload_lds16(Ab + (size_t)row * 512 + kt * 32 + inner, As + (rel >> 1));
      gload_lds16(Bb + (size_t)row * 512 + kt * 32 + inner, Bs + (rel >> 1));
    }
    __syncthreads();
    half8 a[4], b[4];
#pragma unroll
    for (int m = 0; m < 4; ++m)
      a[m] = *(const half8*)&As[swz64(((wr * 64 + m * 16 + c) << 6) + (g << 4)) >> 1];
#pragma unroll
    for (int n = 0; n < 4; ++n)
      b[n] = *(const half8*)&Bs[swz64(((wc * 64 + n * 16 + c) << 6) + (g << 4)) >> 1];
#pragma unroll
    for (int m = 0; m < 4; ++m)
#pragma unroll
      for (int n = 0; n < 4; ++n)
        acc[m][n] = __builtin_amdgcn_mfma_f32_16x16x32_f16(a[m], b[n], acc[m][n], 0, 0, 0);
  }

  const int r0 = wr * 64, c0 = wc * 64;
  if (MODE == 0) {
    half_t* O = ((ct < 4) ? outh : outh2) + (size_t)rt * 128 * 512 + (size_t)(ct & 3) * 128;
#pragma unroll
    for (int m = 0; m < 4; ++m)
#pragma unroll
      for (int j = 0; j < 4; ++j)
#pragma unroll
        for (int n = 0; n < 4; ++n)
          O[(size_t)(r0 + m * 16 + g * 4 + j) * 512 + c0 + n * 16 + c] = (half_t)acc[m][n][j];
  } else if (MODE == 1) {
    half_t* O = outh + (size_t)(ct >> 5) * 2097152 + (size_t)(ct & 31) * 128;
#pragma unroll
    for (int m = 0; m < 4; ++m)
#pragma unroll
      for (int j = 0; j < 4; ++j)
#pragma unroll
        for (int n = 0; n < 4; ++n)
          O[(size_t)(rt * 128 + r0 + m * 16 + g * 4 + j) * 4096 + c0 + n * 16 + c] =
              (half_t)acc[m][n][j];
  } else {
    float* O = outf + (size_t)rt * 128 * 512 + ct * 128;
    float bv[4];
#pragma unroll
    for (int n = 0; n < 4; ++n) bv[n] = bias[ct * 128 + c0 + n * 16 + c];
#pragma unroll
    for (int m = 0; m < 4; ++m)
#pragma unroll
      for (int j = 0; j < 4; ++j)
#pragma unroll
        for (int n = 0; n < 4; ++n)
          O[(size_t)(r0 + m * 16 + g * 4 + j) * 512 + c0 + n * 16 + c] = acc[m][n][j] + bv[n];
  }
}

// ---------------- flash attention v10 ----------------
// v9 base (verified) + T15 in-wave MFMA/VALU overlap: two score tiles in
// flight (sA/sB ping-pong via 2x-unrolled loop). Round r: QK-MFMA(tile r)
// source-interleaved with exp+pack(tile r-1), then PV(r-1). 5-slot K/V ring
// (80KB LDS, 2 blocks/CU), counted vmcnt(8) as v9, stage(r+3) per round.
__global__ __launch_bounds__(256, 2) void attn_kernel(
    const half_t* __restrict__ Q16, const half_t* __restrict__ K16,
    const half_t* __restrict__ Vt, half_t* __restrict__ O16) {
  // [0,40K): K slots [5][64 key][64 d]; [40K,80K): V slots [5][64 d][64 key].
  // Epilogue: red reuses [0,32K), redl [32K,33K).
  __shared__ __attribute__((aligned(16))) char smem[81920];
  half_t* kb_lds = (half_t*)smem;
  half_t* vb_lds = (half_t*)(smem + 40960);

  const int tid = threadIdx.x;
  const int w = tid >> 6, l = tid & 63, lo = l & 31, h = l >> 5;
  const int kw = w >> 1, qw = w & 1;
  // bijective XCD swizzle: 512 blocks -> chunks of 64 per XCD
  const int bid = (blockIdx.x & 7) * 64 + (blockIdx.x >> 3);
  const int bh = bid >> 5, qt = bid & 31;
  const int b = bh >> 3, hh = bh & 7;

  const half_t* Qb = Q16 + (size_t)(b * 4096 + qt * 128 + qw * 64) * 512 + hh * 64;
  const half_t* Kb = K16 + (size_t)b * 4096 * 512 + hh * 64;
  const half_t* Vb = Vt + (size_t)bh * 262144;  // [64 d][4096 s]
  half_t* Ob = O16 + (size_t)(b * 4096 + qt * 128 + qw * 64) * 512 + hh * 64;

  // Q fragments (B-operand): row q = qm*32+lo, elems d = ks*16 + h*8 .. +7
  half8 qa[2][4];
#pragma unroll
  for (int qm = 0; qm < 2; ++qm)
#pragma unroll
    for (int ks = 0; ks < 4; ++ks)
      qa[qm][ks] = *(const half8*)(Qb + (size_t)(qm * 32 + lo) * 512 + ks * 16 + h * 8);

  floatx16 acc[2][2];
#pragma unroll
  for (int qm = 0; qm < 2; ++qm)
#pragma unroll
    for (int dn = 0; dn < 2; ++dn)
#pragma unroll
      for (int r = 0; r < 16; ++r) acc[qm][dn][r] = 0.f;
  float lf[2] = {0.f, 0.f};

  floatx16 fz16;
#pragma unroll
  for (int r = 0; r < 16; ++r) fz16[r] = 0.f;

  // stage K/V tile t (64 keys) into slot (8KB each side); 4 gload per thread
  auto stage = [&](int slot, int t) {
#pragma unroll
    for (int i = 0; i < 2; ++i) {
      int rel = i * 4096 + tid * 16;
      int lg = swz128(rel);
      int row = lg >> 7, inner = (lg & 127) >> 1;
      gload_lds16(Kb + (size_t)(t * 64 + row) * 512 + inner,
                  kb_lds + slot * 4096 + (rel >> 1));
      gload_lds16(Vb + (size_t)row * 4096 + t * 64 + inner,
                  vb_lds + slot * 4096 + (rel >> 1));
    }
  };

  // QK only (round 0): sNew = K[slotQK] . Q^T
  auto qk_only = [&](int slotQK, floatx16 (&sNew)[2]) {
    const half_t* kt = kb_lds + slotQK * 4096;
#pragma unroll
    for (int ks = 0; ks < 4; ++ks) {
      int byte = ((kw * 32 + lo) << 7) + (ks << 5) + (h << 4);
      half8 ka = *(const half8*)&kt[swz128(byte) >> 1];
      if (ks == 0) {
        sNew[0] = __builtin_amdgcn_mfma_f32_32x32x16_f16(ka, qa[0][0], fz16, 0, 0, 0);
        sNew[1] = __builtin_amdgcn_mfma_f32_32x32x16_f16(ka, qa[1][0], fz16, 0, 0, 0);
      } else {
        sNew[0] = __builtin_amdgcn_mfma_f32_32x32x16_f16(ka, qa[0][ks], sNew[0], 0, 0, 0);
        sNew[1] = __builtin_amdgcn_mfma_f32_32x32x16_f16(ka, qa[1][ks], sNew[1], 0, 0, 0);
      }
    }
  };

  // exp+pack one 8-value chunk of sOld -> pa[qm][ksb]
  auto chunk = [&](floatx16 (&sOld)[2], int qm, int ksb, uint4v (&pa)[2][2]) {
    float e[8];
    float ps = 0.f;
#pragma unroll
    for (int j = 0; j < 8; ++j) {
      e[j] = __builtin_amdgcn_exp2f(sOld[qm][8 * ksb + j]);
      ps += e[j];
    }
    lf[qm] += ps;
    uint x0 = pkrtz(e[0], e[1]), x1 = pkrtz(e[2], e[3]);
    uint y0 = pkrtz(e[4], e[5]), y1 = pkrtz(e[6], e[7]);
    pl32swap(x0, y0);
    pl32swap(x1, y1);
    pa[qm][ksb] = (uint4v){x0, x1, y0, y1};
  };

  // PV: acc += P(pa) . V[slotPV]
  auto pv = [&](int slotPV, uint4v (&pa)[2][2]) {
    const half_t* vt = vb_lds + slotPV * 4096;
    __builtin_amdgcn_s_setprio(1);
#pragma unroll
    for (int dn = 0; dn < 2; ++dn)
#pragma unroll
      for (int ks = 0; ks < 2; ++ks) {
        int byte = ((dn * 32 + lo) << 7) + ((kw * 32 + ks * 16 + h * 8) << 1);
        half8 vb = *(const half8*)&vt[swz128(byte) >> 1];
#pragma unroll
        for (int qm = 0; qm < 2; ++qm)
          acc[qm][dn] =
              __builtin_amdgcn_mfma_f32_32x32x16_f16(as_h8(pa[qm][ks]), vb, acc[qm][dn], 0, 0, 0);
      }
    __builtin_amdgcn_s_setprio(0);
  };

  // full round: QK(slotQK)->sNew interleaved with exp+pack(sOld), then PV
  auto full_round = [&](int slotQK, int slotPV, floatx16 (&sOld)[2], floatx16 (&sNew)[2]) {
    const half_t* kt = kb_lds + slotQK * 4096;
    uint4v pa[2][2];
#pragma unroll
    for (int ks = 0; ks < 4; ++ks) {
      int byte = ((kw * 32 + lo) << 7) + (ks << 5) + (h << 4);
      half8 ka = *(const half8*)&kt[swz128(byte) >> 1];
      if (ks == 0) {
        sNew[0] = __builtin_amdgcn_mfma_f32_32x32x16_f16(ka, qa[0][0], fz16, 0, 0, 0);
        sNew[1] = __builtin_amdgcn_mfma_f32_32x32x16_f16(ka, qa[1][0], fz16, 0, 0, 0);
      } else {
        sNew[0] = __builtin_amdgcn_mfma_f32_32x32x16_f16(ka, qa[0][ks], sNew[0], 0, 0, 0);
        sNew[1] = __builtin_amdgcn_mfma_f32_32x32x16_f16(ka, qa[1][ks], sNew[1], 0, 0, 0);
      }
      // independent VALU for the MFMA shadow: finish one 8-chunk of prev tile
      chunk(sOld, ks >> 1, ks & 1, pa);
    }
    pv(slotPV, pa);
  };

  floatx16 sA[2], sB[2];

  // prologue: 3 tiles in flight
  stage(0, 0);
  stage(1, 1);
  stage(2, 2);

  // round 0: QK(0) -> sA
  WAITB(8)
  stage(3, 3);
  qk_only(0, sA);

  // rounds 1..60 in ping-pong pairs; round r: stage(r+3), QK(r), finish(r-1)
  int sStage = 4, sQK = 1, sPV = 0;
  for (int r = 1; r <= 60; r += 2) {
    WAITB(8)
    stage(sStage, r + 3);
    full_round(sQK, sPV, sA, sB);  // QK(r)->sB, finish(r-1) from sA
    sStage = (sStage == 4) ? 0 : sStage + 1;
    sQK = (sQK == 4) ? 0 : sQK + 1;
    sPV = (sPV == 4) ? 0 : sPV + 1;

    WAITB(8)
    stage(sStage, r + 4);
    full_round(sQK, sPV, sB, sA);  // QK(r+1)->sA, finish(r) from sB
    sStage = (sStage == 4) ? 0 : sStage + 1;
    sQK = (sQK == 4) ? 0 : sQK + 1;
    sPV = (sPV == 4) ? 0 : sPV + 1;
  }
  // rounds 61..63 (no staging; tiles 61,62,63 outstanding -> 8/4/0)
  WAITB(8)
  full_round(sQK, sPV, sA, sB);  // QK(61)->sB, finish(60) from sA
  sQK = (sQK == 4) ? 0 : sQK + 1;
  sPV = (sPV == 4) ? 0 : sPV + 1;
  WAITB(4)
  full_round(sQK, sPV, sB, sA);  // QK(62)->sA, finish(61) from sB
  sQK = (sQK == 4) ? 0 : sQK + 1;
  sPV = (sPV == 4) ? 0 : sPV + 1;
  WAITB(0)
  full_round(sQK, sPV, sA, sB);  // QK(63)->sB, finish(62) from sA
  sPV = (sPV == 4) ? 0 : sPV + 1;

  // post: finish(63) from sB, PV slot = 63 % 5 = 3
  {
    uint4v pa[2][2];
#pragma unroll
    for (int ks = 0; ks < 4; ++ks) chunk(sB, ks >> 1, ks & 1, pa);
    pv(sPV, pa);
  }

  // ---- cross-wave (k-half) reduction + normalize + store (v6 verbatim) ----
#pragma unroll
  for (int qm = 0; qm < 2; ++qm) lf[qm] += __shfl_xor(lf[qm], 32);

  float* red = (float*)smem;             // 32 KB: [qw][qm][dn][r][lane]
  float* redl = (float*)(smem + 32768);  // 1 KB: [qw][qm][lane]

  __syncthreads();
  if (kw == 1) {
#pragma unroll
    for (int qm = 0; qm < 2; ++qm) {
      redl[(qw * 2 + qm) * 64 + l] = lf[qm];
#pragma unroll
      for (int dn = 0; dn < 2; ++dn)
#pragma unroll
        for (int r = 0; r < 16; ++r)
          red[((((qw * 2 + qm) * 2 + dn) * 16) + r) * 64 + l] = acc[qm][dn][r];
    }
  }
  __syncthreads();
  if (kw == 0) {
    float inv[2];
#pragma unroll
    for (int qm = 0; qm < 2; ++qm)
      inv[qm] = 1.0f / (lf[qm] + redl[(qw * 2 + qm) * 64 + l]);
#pragma unroll
    for (int qm = 0; qm < 2; ++qm)
#pragma unroll
      for (int r = 0; r < 16; ++r) {
        int ro = (r & 3) + 8 * (r >> 2) + 4 * h;
        float iv = __shfl(inv[qm], ro);
#pragma unroll
        for (int dn = 0; dn < 2; ++dn) {
          float o = (acc[qm][dn][r] + red[((((qw * 2 + qm) * 2 + dn) * 16) + r) * 64 + l]) * iv;
          Ob[(size_t)(qm * 32 + ro) * 512 + dn * 32 + lo] = (half_t)o;
        }
      }
  }
}

extern "C" void kernel_launch(void* const* d_in, const int* in_sizes, int n_in,
                              void* d_out, int out_size, void* d_ws, size_t ws_size,
                              hipStream_t stream) {
  const float* X  = (const float*)d_in[0];
  const float* Wq = (const float*)d_in[1];
  const float* Wk = (const float*)d_in[2];
  const float* Wv = (const float*)d_in[3];
  const float* Wo = (const float*)d_in[4];
  const float* bo = (const float*)d_in[5];
  float* out = (float*)d_out;

  char* ws = (char*)d_ws;
  half_t* X16  = (half_t*)(ws);                 // 8 MB
  half_t* W16  = (half_t*)(ws + 8388608);       // 2 MB (Wq|Wk|Wv|Wo)
  half_t* Q16  = (half_t*)(ws + 10485760);      // 8 MB
  half_t* K16  = (half_t*)(ws + 18874368);      // 8 MB
  half_t* VtW  = (half_t*)(ws + 27262976);      // 8 MB  [B][H][64][4096]
  half_t* O16  = (half_t*)(ws + 35651584);      // 8 MB
  half_t* Wq16 = W16;
  half_t* Wk16 = W16 + 262144;
  half_t* Wv16 = W16 + 524288;
  half_t* Wo16 = W16 + 786432;

  cvt_x_kernel<<<2048, 256, 0, stream>>>(X, X16);
  cvt_w_kernel<<<512, 256, 0, stream>>>(Wq, Wk, Wv, Wo, W16);
  gemm_nt<0><<<512, 256, 0, stream>>>(X16, Wq16, Wk16, Q16, K16, nullptr, nullptr);
  gemm_nt<1><<<256, 256, 0, stream>>>(Wv16, X16, nullptr, VtW, nullptr, nullptr, nullptr);
  attn_kernel<<<512, 256, 0, stream>>>(Q16, K16, VtW, O16);
  gemm_nt<2><<<256, 256, 0, stream>>>(O16, Wo16, nullptr, nullptr, nullptr, out, bo);
}

// Round 12
// 122.114 us; speedup vs baseline: 1.1411x; 1.0986x over previous
//
#include <hip/hip_runtime.h>
#include <stdint.h>

typedef _Float16 half_t;
typedef _Float16 half8 __attribute__((ext_vector_type(8)));
typedef __fp16 fp16x2 __attribute__((ext_vector_type(2)));
typedef float floatx4 __attribute__((ext_vector_type(4)));
typedef float floatx16 __attribute__((ext_vector_type(16)));
typedef unsigned int uint;
typedef unsigned int uint4v __attribute__((ext_vector_type(4)));

#define LOG2E 1.4426950408889634f

__device__ __forceinline__ void gload_lds16(const void* g, void* l) {
  __builtin_amdgcn_global_load_lds(
      (__attribute__((address_space(1))) void*)(uintptr_t)g,
      (__attribute__((address_space(3))) void*)(uintptr_t)l, 16, 0, 0);
}

// involution swizzles: XOR byte bits 4..6 with low row bits (keeps 16B alignment)
__device__ __forceinline__ int swz64(int b)  { return b ^ (((b >> 7) & 3) << 4); }   // 64B rows
__device__ __forceinline__ int swz128(int b) { return b ^ (((b >> 7) & 7) << 4); }   // 128B rows

__device__ __forceinline__ uint pkrtz(float a, float b) {
  union { fp16x2 h; uint u; } cv;
  cv.h = __builtin_amdgcn_cvt_pkrtz(a, b);
  return cv.u;
}
__device__ __forceinline__ void pl32swap(uint &x, uint &y) {
  asm("v_permlane32_swap_b32 %0, %1" : "+v"(x), "+v"(y));
}
__device__ __forceinline__ half8 as_h8(uint4v v) {
  union { uint4v u; half8 h; } c; c.u = v; return c.h;
}

#define WAITB(N)                                          \
  asm volatile("s_waitcnt vmcnt(" #N ")" ::: "memory");   \
  __builtin_amdgcn_s_barrier();                           \
  __builtin_amdgcn_sched_barrier(0);

// ---------------- fused fp32 -> fp16 converts (X and all W) ----------------
__global__ void cvt_kernel(const float* __restrict__ X, const float* __restrict__ Wq,
                           const float* __restrict__ Wk, const float* __restrict__ Wv,
                           const float* __restrict__ Wo, half_t* __restrict__ X16,
                           half_t* __restrict__ W16) {
  int gid = blockIdx.x;
  if (gid < 2048) {
    int i = (gid * 256 + threadIdx.x) * 8;
    float4 u = *(const float4*)(X + i);
    float4 v = *(const float4*)(X + i + 4);
    half8 o = {(half_t)u.x, (half_t)u.y, (half_t)u.z, (half_t)u.w,
               (half_t)v.x, (half_t)v.y, (half_t)v.z, (half_t)v.w};
    *(half8*)(X16 + i) = o;
  } else {
    int i = (gid - 2048) * 256 + threadIdx.x;
    int widx = i >> 15;
    int j = (i & 32767) * 8;
    const float* src = (widx == 0) ? Wq : (widx == 1) ? Wk : (widx == 2) ? Wv : Wo;
    float sc = (widx == 0) ? 0.125f * LOG2E : 1.0f;  // fold 1/sqrt(64) AND log2(e) into Wq
    float4 u = *(const float4*)(src + j);
    float4 v = *(const float4*)(src + j + 4);
    half8 o = {(half_t)(u.x * sc), (half_t)(u.y * sc), (half_t)(u.z * sc), (half_t)(u.w * sc),
               (half_t)(v.x * sc), (half_t)(v.y * sc), (half_t)(v.z * sc), (half_t)(v.w * sc)};
    *(half8*)(W16 + widx * 262144 + j) = o;
  }
}

// ---------------- NT fp16 GEMM, 128x128 tile, BK=32, K=512 ----------------
// T3/T4 ring schedule: 4-slot As/Bs ring, counted vmcnt(8), stage(kt+3) per
// round, tail 8/4/0. Fragment math and output identical to the verified
// 2-barrier version (same kt order -> bit-identical results).
template <int MODE>
__global__ __launch_bounds__(256) void gemm_nt(
    const half_t* __restrict__ A, const half_t* __restrict__ B0,
    const half_t* __restrict__ B1, half_t* __restrict__ outh,
    half_t* __restrict__ outh2, float* __restrict__ outf,
    const float* __restrict__ bias) {
  __shared__ __attribute__((aligned(16))) half_t As[4][4096];  // 32 KB
  __shared__ __attribute__((aligned(16))) half_t Bs[4][4096];  // 32 KB

  const int tid = threadIdx.x;
  const int w = tid >> 6, l = tid & 63, g = l >> 4, c = l & 15;
  const int wr = w >> 1, wc = w & 1;
  const int bidx = blockIdx.x;

  int rt, ct;
  const half_t *Ab, *Bb;
  if (MODE == 0) {
    rt = bidx >> 3; ct = bidx & 7;
    Ab = A + (size_t)rt * 128 * 512;
    Bb = ((ct < 4) ? B0 : B1) + (size_t)(ct & 3) * 128 * 512;
  } else if (MODE == 1) {
    rt = bidx >> 6; ct = bidx & 63;
    Ab = A + (size_t)rt * 128 * 512;
    Bb = B0 + (size_t)ct * 128 * 512;
  } else {
    rt = bidx >> 2; ct = bidx & 3;
    Ab = A + (size_t)rt * 128 * 512;
    Bb = B0 + (size_t)ct * 128 * 512;
  }

  const floatx4 fzero = {0.f, 0.f, 0.f, 0.f};
  floatx4 acc[4][4];
#pragma unroll
  for (int m = 0; m < 4; ++m)
#pragma unroll
    for (int n = 0; n < 4; ++n) acc[m][n] = fzero;

  // stage K-step kt into ring slot (8KB A + 8KB B); 4 gload_lds per thread
  auto stage = [&](int slot, int kt) {
#pragma unroll
    for (int i = 0; i < 2; ++i) {
      int rel = i * 4096 + tid * 16;
      int lg = swz64(rel);
      int row = lg >> 6, inner = (lg & 63) >> 1;
      gload_lds16(Ab + (size_t)row * 512 + kt * 32 + inner, As[slot] + (rel >> 1));
      gload_lds16(Bb + (size_t)row * 512 + kt * 32 + inner, Bs[slot] + (rel >> 1));
    }
  };

  auto compute = [&](int slot) {
    half8 a[4], b[4];
#pragma unroll
    for (int m = 0; m < 4; ++m)
      a[m] = *(const half8*)&As[slot][swz64(((wr * 64 + m * 16 + c) << 6) + (g << 4)) >> 1];
#pragma unroll
    for (int n = 0; n < 4; ++n)
      b[n] = *(const half8*)&Bs[slot][swz64(((wc * 64 + n * 16 + c) << 6) + (g << 4)) >> 1];
#pragma unroll
    for (int m = 0; m < 4; ++m)
#pragma unroll
      for (int n = 0; n < 4; ++n)
        acc[m][n] = __builtin_amdgcn_mfma_f32_16x16x32_f16(a[m], b[n], acc[m][n], 0, 0, 0);
  };

  // prologue: 3 K-steps in flight (12 outstanding gload_lds per thread)
  stage(0, 0);
  stage(1, 1);
  stage(2, 2);

  for (int kt = 0; kt < 13; ++kt) {
    WAITB(8)
    stage((kt + 3) & 3, kt + 3);
    compute(kt & 3);
  }
  WAITB(8)
  compute(1);
  WAITB(4)
  compute(2);
  WAITB(0)
  compute(3);

  const int r0 = wr * 64, c0 = wc * 64;
  if (MODE == 0) {
    half_t* O = ((ct < 4) ? outh : outh2) + (size_t)rt * 128 * 512 + (size_t)(ct & 3) * 128;
#pragma unroll
    for (int m = 0; m < 4; ++m)
#pragma unroll
      for (int j = 0; j < 4; ++j)
#pragma unroll
        for (int n = 0; n < 4; ++n)
          O[(size_t)(r0 + m * 16 + g * 4 + j) * 512 + c0 + n * 16 + c] = (half_t)acc[m][n][j];
  } else if (MODE == 1) {
    half_t* O = outh + (size_t)(ct >> 5) * 2097152 + (size_t)(ct & 31) * 128;
#pragma unroll
    for (int m = 0; m < 4; ++m)
#pragma unroll
      for (int j = 0; j < 4; ++j)
#pragma unroll
        for (int n = 0; n < 4; ++n)
          O[(size_t)(rt * 128 + r0 + m * 16 + g * 4 + j) * 4096 + c0 + n * 16 + c] =
              (half_t)acc[m][n][j];
  } else {
    float* O = outf + (size_t)rt * 128 * 512 + ct * 128;
    float bv[4];
#pragma unroll
    for (int n = 0; n < 4; ++n) bv[n] = bias[ct * 128 + c0 + n * 16 + c];
#pragma unroll
    for (int m = 0; m < 4; ++m)
#pragma unroll
      for (int j = 0; j < 4; ++j)
#pragma unroll
        for (int n = 0; n < 4; ++n)
          O[(size_t)(r0 + m * 16 + g * 4 + j) * 512 + c0 + n * 16 + c] = acc[m][n][j] + bv[n];
  }
}

// ---------------- flash attention v10 (verified, kept byte-for-byte) ----------------
__global__ __launch_bounds__(256, 2) void attn_kernel(
    const half_t* __restrict__ Q16, const half_t* __restrict__ K16,
    const half_t* __restrict__ Vt, half_t* __restrict__ O16) {
  // [0,40K): K slots [5][64 key][64 d]; [40K,80K): V slots [5][64 d][64 key].
  // Epilogue: red reuses [0,32K), redl [32K,33K).
  __shared__ __attribute__((aligned(16))) char smem[81920];
  half_t* kb_lds = (half_t*)smem;
  half_t* vb_lds = (half_t*)(smem + 40960);

  const int tid = threadIdx.x;
  const int w = tid >> 6, l = tid & 63, lo = l & 31, h = l >> 5;
  const int kw = w >> 1, qw = w & 1;
  // bijective XCD swizzle: 512 blocks -> chunks of 64 per XCD
  const int bid = (blockIdx.x & 7) * 64 + (blockIdx.x >> 3);
  const int bh = bid >> 5, qt = bid & 31;
  const int b = bh >> 3, hh = bh & 7;

  const half_t* Qb = Q16 + (size_t)(b * 4096 + qt * 128 + qw * 64) * 512 + hh * 64;
  const half_t* Kb = K16 + (size_t)b * 4096 * 512 + hh * 64;
  const half_t* Vb = Vt + (size_t)bh * 262144;  // [64 d][4096 s]
  half_t* Ob = O16 + (size_t)(b * 4096 + qt * 128 + qw * 64) * 512 + hh * 64;

  // Q fragments (B-operand): row q = qm*32+lo, elems d = ks*16 + h*8 .. +7
  half8 qa[2][4];
#pragma unroll
  for (int qm = 0; qm < 2; ++qm)
#pragma unroll
    for (int ks = 0; ks < 4; ++ks)
      qa[qm][ks] = *(const half8*)(Qb + (size_t)(qm * 32 + lo) * 512 + ks * 16 + h * 8);

  floatx16 acc[2][2];
#pragma unroll
  for (int qm = 0; qm < 2; ++qm)
#pragma unroll
    for (int dn = 0; dn < 2; ++dn)
#pragma unroll
      for (int r = 0; r < 16; ++r) acc[qm][dn][r] = 0.f;
  float lf[2] = {0.f, 0.f};

  floatx16 fz16;
#pragma unroll
  for (int r = 0; r < 16; ++r) fz16[r] = 0.f;

  // stage K/V tile t (64 keys) into slot (8KB each side); 4 gload per thread
  auto stage = [&](int slot, int t) {
#pragma unroll
    for (int i = 0; i < 2; ++i) {
      int rel = i * 4096 + tid * 16;
      int lg = swz128(rel);
      int row = lg >> 7, inner = (lg & 127) >> 1;
      gload_lds16(Kb + (size_t)(t * 64 + row) * 512 + inner,
                  kb_lds + slot * 4096 + (rel >> 1));
      gload_lds16(Vb + (size_t)row * 4096 + t * 64 + inner,
                  vb_lds + slot * 4096 + (rel >> 1));
    }
  };

  // QK only (round 0): sNew = K[slotQK] . Q^T
  auto qk_only = [&](int slotQK, floatx16 (&sNew)[2]) {
    const half_t* kt = kb_lds + slotQK * 4096;
#pragma unroll
    for (int ks = 0; ks < 4; ++ks) {
      int byte = ((kw * 32 + lo) << 7) + (ks << 5) + (h << 4);
      half8 ka = *(const half8*)&kt[swz128(byte) >> 1];
      if (ks == 0) {
        sNew[0] = __builtin_amdgcn_mfma_f32_32x32x16_f16(ka, qa[0][0], fz16, 0, 0, 0);
        sNew[1] = __builtin_amdgcn_mfma_f32_32x32x16_f16(ka, qa[1][0], fz16, 0, 0, 0);
      } else {
        sNew[0] = __builtin_amdgcn_mfma_f32_32x32x16_f16(ka, qa[0][ks], sNew[0], 0, 0, 0);
        sNew[1] = __builtin_amdgcn_mfma_f32_32x32x16_f16(ka, qa[1][ks], sNew[1], 0, 0, 0);
      }
    }
  };

  // exp+pack one 8-value chunk of sOld -> pa[qm][ksb]
  auto chunk = [&](floatx16 (&sOld)[2], int qm, int ksb, uint4v (&pa)[2][2]) {
    float e[8];
    float ps = 0.f;
#pragma unroll
    for (int j = 0; j < 8; ++j) {
      e[j] = __builtin_amdgcn_exp2f(sOld[qm][8 * ksb + j]);
      ps += e[j];
    }
    lf[qm] += ps;
    uint x0 = pkrtz(e[0], e[1]), x1 = pkrtz(e[2], e[3]);
    uint y0 = pkrtz(e[4], e[5]), y1 = pkrtz(e[6], e[7]);
    pl32swap(x0, y0);
    pl32swap(x1, y1);
    pa[qm][ksb] = (uint4v){x0, x1, y0, y1};
  };

  // PV: acc += P(pa) . V[slotPV]
  auto pv = [&](int slotPV, uint4v (&pa)[2][2]) {
    const half_t* vt = vb_lds + slotPV * 4096;
    __builtin_amdgcn_s_setprio(1);
#pragma unroll
    for (int dn = 0; dn < 2; ++dn)
#pragma unroll
      for (int ks = 0; ks < 2; ++ks) {
        int byte = ((dn * 32 + lo) << 7) + ((kw * 32 + ks * 16 + h * 8) << 1);
        half8 vb = *(const half8*)&vt[swz128(byte) >> 1];
#pragma unroll
        for (int qm = 0; qm < 2; ++qm)
          acc[qm][dn] =
              __builtin_amdgcn_mfma_f32_32x32x16_f16(as_h8(pa[qm][ks]), vb, acc[qm][dn], 0, 0, 0);
      }
    __builtin_amdgcn_s_setprio(0);
  };

  // full round: QK(slotQK)->sNew interleaved with exp+pack(sOld), then PV
  auto full_round = [&](int slotQK, int slotPV, floatx16 (&sOld)[2], floatx16 (&sNew)[2]) {
    const half_t* kt = kb_lds + slotQK * 4096;
    uint4v pa[2][2];
#pragma unroll
    for (int ks = 0; ks < 4; ++ks) {
      int byte = ((kw * 32 + lo) << 7) + (ks << 5) + (h << 4);
      half8 ka = *(const half8*)&kt[swz128(byte) >> 1];
      if (ks == 0) {
        sNew[0] = __builtin_amdgcn_mfma_f32_32x32x16_f16(ka, qa[0][0], fz16, 0, 0, 0);
        sNew[1] = __builtin_amdgcn_mfma_f32_32x32x16_f16(ka, qa[1][0], fz16, 0, 0, 0);
      } else {
        sNew[0] = __builtin_amdgcn_mfma_f32_32x32x16_f16(ka, qa[0][ks], sNew[0], 0, 0, 0);
        sNew[1] = __builtin_amdgcn_mfma_f32_32x32x16_f16(ka, qa[1][ks], sNew[1], 0, 0, 0);
      }
      // independent VALU for the MFMA shadow: finish one 8-chunk of prev tile
      chunk(sOld, ks >> 1, ks & 1, pa);
    }
    pv(slotPV, pa);
  };

  floatx16 sA[2], sB[2];

  // prologue: 3 tiles in flight
  stage(0, 0);
  stage(1, 1);
  stage(2, 2);

  // round 0: QK(0) -> sA
  WAITB(8)
  stage(3, 3);
  qk_only(0, sA);

  // rounds 1..60 in ping-pong pairs; round r: stage(r+3), QK(r), finish(r-1)
  int sStage = 4, sQK = 1, sPV = 0;
  for (int r = 1; r <= 60; r += 2) {
    WAITB(8)
    stage(sStage, r + 3);
    full_round(sQK, sPV, sA, sB);  // QK(r)->sB, finish(r-1) from sA
    sStage = (sStage == 4) ? 0 : sStage + 1;
    sQK = (sQK == 4) ? 0 : sQK + 1;
    sPV = (sPV == 4) ? 0 : sPV + 1;

    WAITB(8)
    stage(sStage, r + 4);
    full_round(sQK, sPV, sB, sA);  // QK(r+1)->sA, finish(r) from sB
    sStage = (sStage == 4) ? 0 : sStage + 1;
    sQK = (sQK == 4) ? 0 : sQK + 1;
    sPV = (sPV == 4) ? 0 : sPV + 1;
  }
  // rounds 61..63 (no staging; tiles 61,62,63 outstanding -> 8/4/0)
  WAITB(8)
  full_round(sQK, sPV, sA, sB);  // QK(61)->sB, finish(60) from sA
  sQK = (sQK == 4) ? 0 : sQK + 1;
  sPV = (sPV == 4) ? 0 : sPV + 1;
  WAITB(4)
  full_round(sQK, sPV, sB, sA);  // QK(62)->sA, finish(61) from sB
  sQK = (sQK == 4) ? 0 : sQK + 1;
  sPV = (sPV == 4) ? 0 : sPV + 1;
  WAITB(0)
  full_round(sQK, sPV, sA, sB);  // QK(63)->sB, finish(62) from sA
  sPV = (sPV == 4) ? 0 : sPV + 1;

  // post: finish(63) from sB, PV slot = 63 % 5 = 3
  {
    uint4v pa[2][2];
#pragma unroll
    for (int ks = 0; ks < 4; ++ks) chunk(sB, ks >> 1, ks & 1, pa);
    pv(sPV, pa);
  }

  // ---- cross-wave (k-half) reduction + normalize + store (v6 verbatim) ----
#pragma unroll
  for (int qm = 0; qm < 2; ++qm) lf[qm] += __shfl_xor(lf[qm], 32);

  float* red = (float*)smem;             // 32 KB: [qw][qm][dn][r][lane]
  float* redl = (float*)(smem + 32768);  // 1 KB: [qw][qm][lane]

  __syncthreads();
  if (kw == 1) {
#pragma unroll
    for (int qm = 0; qm < 2; ++qm) {
      redl[(qw * 2 + qm) * 64 + l] = lf[qm];
#pragma unroll
      for (int dn = 0; dn < 2; ++dn)
#pragma unroll
        for (int r = 0; r < 16; ++r)
          red[((((qw * 2 + qm) * 2 + dn) * 16) + r) * 64 + l] = acc[qm][dn][r];
    }
  }
  __syncthreads();
  if (kw == 0) {
    float inv[2];
#pragma unroll
    for (int qm = 0; qm < 2; ++qm)
      inv[qm] = 1.0f / (lf[qm] + redl[(qw * 2 + qm) * 64 + l]);
#pragma unroll
    for (int qm = 0; qm < 2; ++qm)
#pragma unroll
      for (int r = 0; r < 16; ++r) {
        int ro = (r & 3) + 8 * (r >> 2) + 4 * h;
        float iv = __shfl(inv[qm], ro);
#pragma unroll
        for (int dn = 0; dn < 2; ++dn) {
          float o = (acc[qm][dn][r] + red[((((qw * 2 + qm) * 2 + dn) * 16) + r) * 64 + l]) * iv;
          Ob[(size_t)(qm * 32 + ro) * 512 + dn * 32 + lo] = (half_t)o;
        }
      }
  }
}

extern "C" void kernel_launch(void* const* d_in, const int* in_sizes, int n_in,
                              void* d_out, int out_size, void* d_ws, size_t ws_size,
                              hipStream_t stream) {
  const float* X  = (const float*)d_in[0];
  const float* Wq = (const float*)d_in[1];
  const float* Wk = (const float*)d_in[2];
  const float* Wv = (const float*)d_in[3];
  const float* Wo = (const float*)d_in[4];
  const float* bo = (const float*)d_in[5];
  float* out = (float*)d_out;

  char* ws = (char*)d_ws;
  half_t* X16  = (half_t*)(ws);                 // 8 MB
  half_t* W16  = (half_t*)(ws + 8388608);       // 2 MB (Wq|Wk|Wv|Wo)
  half_t* Q16  = (half_t*)(ws + 10485760);      // 8 MB
  half_t* K16  = (half_t*)(ws + 18874368);      // 8 MB
  half_t* VtW  = (half_t*)(ws + 27262976);      // 8 MB  [B][H][64][4096]
  half_t* O16  = (half_t*)(ws + 35651584);      // 8 MB
  half_t* Wq16 = W16;
  half_t* Wk16 = W16 + 262144;
  half_t* Wv16 = W16 + 524288;
  half_t* Wo16 = W16 + 786432;

  cvt_kernel<<<2560, 256, 0, stream>>>(X, Wq, Wk, Wv, Wo, X16, W16);
  gemm_nt<0><<<512, 256, 0, stream>>>(X16, Wq16, Wk16, Q16, K16, nullptr, nullptr);
  gemm_nt<1><<<256, 256, 0, stream>>>(Wv16, X16, nullptr, VtW, nullptr, nullptr, nullptr);
  attn_kernel<<<512, 256, 0, stream>>>(Q16, K16, VtW, O16);
  gemm_nt<2><<<256, 256, 0, stream>>>(O16, Wo16, nullptr, nullptr, nullptr, out, bo);
}

// Round 13
// 117.956 us; speedup vs baseline: 1.1813x; 1.0353x over previous
//
#include <hip/hip_runtime.h>
#include <stdint.h>

typedef _Float16 half_t;
typedef _Float16 half8 __attribute__((ext_vector_type(8)));
typedef __fp16 fp16x2 __attribute__((ext_vector_type(2)));
typedef float floatx4 __attribute__((ext_vector_type(4)));
typedef float floatx16 __attribute__((ext_vector_type(16)));
typedef unsigned int uint;
typedef unsigned int uint4v __attribute__((ext_vector_type(4)));

#define LOG2E 1.4426950408889634f

__device__ __forceinline__ void gload_lds16(const void* g, void* l) {
  __builtin_amdgcn_global_load_lds(
      (__attribute__((address_space(1))) void*)(uintptr_t)g,
      (__attribute__((address_space(3))) void*)(uintptr_t)l, 16, 0, 0);
}

// involution swizzles: XOR byte bits 4..6 with low row bits (keeps 16B alignment)
__device__ __forceinline__ int swz64(int b)  { return b ^ (((b >> 7) & 3) << 4); }   // 64B rows
__device__ __forceinline__ int swz128(int b) { return b ^ (((b >> 7) & 7) << 4); }   // 128B rows

__device__ __forceinline__ uint pkrtz(float a, float b) {
  union { fp16x2 h; uint u; } cv;
  cv.h = __builtin_amdgcn_cvt_pkrtz(a, b);
  return cv.u;
}
__device__ __forceinline__ void pl32swap(uint &x, uint &y) {
  asm("v_permlane32_swap_b32 %0, %1" : "+v"(x), "+v"(y));
}
__device__ __forceinline__ half8 as_h8(uint4v v) {
  union { uint4v u; half8 h; } c; c.u = v; return c.h;
}

#define WAITB(N)                                          \
  asm volatile("s_waitcnt vmcnt(" #N ")" ::: "memory");   \
  __builtin_amdgcn_s_barrier();                           \
  __builtin_amdgcn_sched_barrier(0);

// ---------------- fused fp32 -> fp16 converts (X and all W) ----------------
__global__ void cvt_kernel(const float* __restrict__ X, const float* __restrict__ Wq,
                           const float* __restrict__ Wk, const float* __restrict__ Wv,
                           const float* __restrict__ Wo, half_t* __restrict__ X16,
                           half_t* __restrict__ W16) {
  int gid = blockIdx.x;
  if (gid < 2048) {
    int i = (gid * 256 + threadIdx.x) * 8;
    float4 u = *(const float4*)(X + i);
    float4 v = *(const float4*)(X + i + 4);
    half8 o = {(half_t)u.x, (half_t)u.y, (half_t)u.z, (half_t)u.w,
               (half_t)v.x, (half_t)v.y, (half_t)v.z, (half_t)v.w};
    *(half8*)(X16 + i) = o;
  } else {
    int i = (gid - 2048) * 256 + threadIdx.x;
    int widx = i >> 15;
    int j = (i & 32767) * 8;
    const float* src = (widx == 0) ? Wq : (widx == 1) ? Wk : (widx == 2) ? Wv : Wo;
    float sc = (widx == 0) ? 0.125f * LOG2E : 1.0f;  // fold 1/sqrt(64) AND log2(e) into Wq
    float4 u = *(const float4*)(src + j);
    float4 v = *(const float4*)(src + j + 4);
    half8 o = {(half_t)(u.x * sc), (half_t)(u.y * sc), (half_t)(u.z * sc), (half_t)(u.w * sc),
               (half_t)(v.x * sc), (half_t)(v.y * sc), (half_t)(v.z * sc), (half_t)(v.w * sc)};
    *(half8*)(W16 + widx * 262144 + j) = o;
  }
}

// ---------------- NT fp16 GEMM body, 128x128 tile, BK=32, K=512 ----------------
// T3/T4 ring schedule (verified r12). bidx is the MODE-local, XCD-swizzled id.
template <int MODE>
__device__ __forceinline__ void gemm_body(
    int bidx, const half_t* __restrict__ A, const half_t* __restrict__ B0,
    const half_t* __restrict__ B1, half_t* __restrict__ outh,
    half_t* __restrict__ outh2, float* __restrict__ outf,
    const float* __restrict__ bias, half_t (*As)[4096], half_t (*Bs)[4096]) {
  const int tid = threadIdx.x;
  const int w = tid >> 6, l = tid & 63, g = l >> 4, c = l & 15;
  const int wr = w >> 1, wc = w & 1;

  int rt, ct;
  const half_t *Ab, *Bb;
  if (MODE == 0) {
    rt = bidx >> 3; ct = bidx & 7;
    Ab = A + (size_t)rt * 128 * 512;
    Bb = ((ct < 4) ? B0 : B1) + (size_t)(ct & 3) * 128 * 512;
  } else if (MODE == 1) {
    rt = bidx >> 6; ct = bidx & 63;
    Ab = A + (size_t)rt * 128 * 512;
    Bb = B0 + (size_t)ct * 128 * 512;
  } else {
    rt = bidx >> 2; ct = bidx & 3;
    Ab = A + (size_t)rt * 128 * 512;
    Bb = B0 + (size_t)ct * 128 * 512;
  }

  const floatx4 fzero = {0.f, 0.f, 0.f, 0.f};
  floatx4 acc[4][4];
#pragma unroll
  for (int m = 0; m < 4; ++m)
#pragma unroll
    for (int n = 0; n < 4; ++n) acc[m][n] = fzero;

  auto stage = [&](int slot, int kt) {
#pragma unroll
    for (int i = 0; i < 2; ++i) {
      int rel = i * 4096 + tid * 16;
      int lg = swz64(rel);
      int row = lg >> 6, inner = (lg & 63) >> 1;
      gload_lds16(Ab + (size_t)row * 512 + kt * 32 + inner, As[slot] + (rel >> 1));
      gload_lds16(Bb + (size_t)row * 512 + kt * 32 + inner, Bs[slot] + (rel >> 1));
    }
  };

  auto compute = [&](int slot) {
    half8 a[4], b[4];
#pragma unroll
    for (int m = 0; m < 4; ++m)
      a[m] = *(const half8*)&As[slot][swz64(((wr * 64 + m * 16 + c) << 6) + (g << 4)) >> 1];
#pragma unroll
    for (int n = 0; n < 4; ++n)
      b[n] = *(const half8*)&Bs[slot][swz64(((wc * 64 + n * 16 + c) << 6) + (g << 4)) >> 1];
#pragma unroll
    for (int m = 0; m < 4; ++m)
#pragma unroll
      for (int n = 0; n < 4; ++n)
        acc[m][n] = __builtin_amdgcn_mfma_f32_16x16x32_f16(a[m], b[n], acc[m][n], 0, 0, 0);
  };

  stage(0, 0);
  stage(1, 1);
  stage(2, 2);

  for (int kt = 0; kt < 13; ++kt) {
    WAITB(8)
    stage((kt + 3) & 3, kt + 3);
    compute(kt & 3);
  }
  WAITB(8)
  compute(1);
  WAITB(4)
  compute(2);
  WAITB(0)
  compute(3);

  const int r0 = wr * 64, c0 = wc * 64;
  if (MODE == 0) {
    half_t* O = ((ct < 4) ? outh : outh2) + (size_t)rt * 128 * 512 + (size_t)(ct & 3) * 128;
#pragma unroll
    for (int m = 0; m < 4; ++m)
#pragma unroll
      for (int j = 0; j < 4; ++j)
#pragma unroll
        for (int n = 0; n < 4; ++n)
          O[(size_t)(r0 + m * 16 + g * 4 + j) * 512 + c0 + n * 16 + c] = (half_t)acc[m][n][j];
  } else if (MODE == 1) {
    half_t* O = outh + (size_t)(ct >> 5) * 2097152 + (size_t)(ct & 31) * 128;
#pragma unroll
    for (int m = 0; m < 4; ++m)
#pragma unroll
      for (int j = 0; j < 4; ++j)
#pragma unroll
        for (int n = 0; n < 4; ++n)
          O[(size_t)(rt * 128 + r0 + m * 16 + g * 4 + j) * 4096 + c0 + n * 16 + c] =
              (half_t)acc[m][n][j];
  } else {
    float* O = outf + (size_t)rt * 128 * 512 + ct * 128;
    float bv[4];
#pragma unroll
    for (int n = 0; n < 4; ++n) bv[n] = bias[ct * 128 + c0 + n * 16 + c];
#pragma unroll
    for (int m = 0; m < 4; ++m)
#pragma unroll
      for (int j = 0; j < 4; ++j)
#pragma unroll
        for (int n = 0; n < 4; ++n)
          O[(size_t)(r0 + m * 16 + g * 4 + j) * 512 + c0 + n * 16 + c] = acc[m][n][j] + bv[n];
  }
}

// fused Q/K-proj (blocks 0..511, MODE 0) + V^T-proj (512..767, MODE 1);
// per-mode bijective XCD swizzle.
__global__ __launch_bounds__(256) void gemm01_kernel(
    const half_t* __restrict__ X16, const half_t* __restrict__ Wq16,
    const half_t* __restrict__ Wk16, const half_t* __restrict__ Wv16,
    half_t* __restrict__ Q16, half_t* __restrict__ K16, half_t* __restrict__ VtW) {
  __shared__ __attribute__((aligned(16))) half_t As[4][4096];
  __shared__ __attribute__((aligned(16))) half_t Bs[4][4096];
  int x = blockIdx.x;
  if (x < 512) {
    int bid = (x & 7) * 64 + (x >> 3);
    gemm_body<0>(bid, X16, Wq16, Wk16, Q16, K16, nullptr, nullptr, As, Bs);
  } else {
    int lb = x - 512;
    int bid = (lb & 7) * 32 + (lb >> 3);
    gemm_body<1>(bid, Wv16, X16, nullptr, VtW, nullptr, nullptr, nullptr, As, Bs);
  }
}

// O-projection (+bias), 256 blocks, XCD swizzle.
__global__ __launch_bounds__(256) void gemm2_kernel(
    const half_t* __restrict__ O16, const half_t* __restrict__ Wo16,
    float* __restrict__ out, const float* __restrict__ bias) {
  __shared__ __attribute__((aligned(16))) half_t As[4][4096];
  __shared__ __attribute__((aligned(16))) half_t Bs[4][4096];
  int x = blockIdx.x;
  int bid = (x & 7) * 32 + (x >> 3);
  gemm_body<2>(bid, O16, Wo16, nullptr, nullptr, nullptr, out, bias, As, Bs);
}

// ---------------- flash attention v10 (verified, kept byte-for-byte) ----------------
__global__ __launch_bounds__(256, 2) void attn_kernel(
    const half_t* __restrict__ Q16, const half_t* __restrict__ K16,
    const half_t* __restrict__ Vt, half_t* __restrict__ O16) {
  // [0,40K): K slots [5][64 key][64 d]; [40K,80K): V slots [5][64 d][64 key].
  // Epilogue: red reuses [0,32K), redl [32K,33K).
  __shared__ __attribute__((aligned(16))) char smem[81920];
  half_t* kb_lds = (half_t*)smem;
  half_t* vb_lds = (half_t*)(smem + 40960);

  const int tid = threadIdx.x;
  const int w = tid >> 6, l = tid & 63, lo = l & 31, h = l >> 5;
  const int kw = w >> 1, qw = w & 1;
  // bijective XCD swizzle: 512 blocks -> chunks of 64 per XCD
  const int bid = (blockIdx.x & 7) * 64 + (blockIdx.x >> 3);
  const int bh = bid >> 5, qt = bid & 31;
  const int b = bh >> 3, hh = bh & 7;

  const half_t* Qb = Q16 + (size_t)(b * 4096 + qt * 128 + qw * 64) * 512 + hh * 64;
  const half_t* Kb = K16 + (size_t)b * 4096 * 512 + hh * 64;
  const half_t* Vb = Vt + (size_t)bh * 262144;  // [64 d][4096 s]
  half_t* Ob = O16 + (size_t)(b * 4096 + qt * 128 + qw * 64) * 512 + hh * 64;

  // Q fragments (B-operand): row q = qm*32+lo, elems d = ks*16 + h*8 .. +7
  half8 qa[2][4];
#pragma unroll
  for (int qm = 0; qm < 2; ++qm)
#pragma unroll
    for (int ks = 0; ks < 4; ++ks)
      qa[qm][ks] = *(const half8*)(Qb + (size_t)(qm * 32 + lo) * 512 + ks * 16 + h * 8);

  floatx16 acc[2][2];
#pragma unroll
  for (int qm = 0; qm < 2; ++qm)
#pragma unroll
    for (int dn = 0; dn < 2; ++dn)
#pragma unroll
      for (int r = 0; r < 16; ++r) acc[qm][dn][r] = 0.f;
  float lf[2] = {0.f, 0.f};

  floatx16 fz16;
#pragma unroll
  for (int r = 0; r < 16; ++r) fz16[r] = 0.f;

  // stage K/V tile t (64 keys) into slot (8KB each side); 4 gload per thread
  auto stage = [&](int slot, int t) {
#pragma unroll
    for (int i = 0; i < 2; ++i) {
      int rel = i * 4096 + tid * 16;
      int lg = swz128(rel);
      int row = lg >> 7, inner = (lg & 127) >> 1;
      gload_lds16(Kb + (size_t)(t * 64 + row) * 512 + inner,
                  kb_lds + slot * 4096 + (rel >> 1));
      gload_lds16(Vb + (size_t)row * 4096 + t * 64 + inner,
                  vb_lds + slot * 4096 + (rel >> 1));
    }
  };

  // QK only (round 0): sNew = K[slotQK] . Q^T
  auto qk_only = [&](int slotQK, floatx16 (&sNew)[2]) {
    const half_t* kt = kb_lds + slotQK * 4096;
#pragma unroll
    for (int ks = 0; ks < 4; ++ks) {
      int byte = ((kw * 32 + lo) << 7) + (ks << 5) + (h << 4);
      half8 ka = *(const half8*)&kt[swz128(byte) >> 1];
      if (ks == 0) {
        sNew[0] = __builtin_amdgcn_mfma_f32_32x32x16_f16(ka, qa[0][0], fz16, 0, 0, 0);
        sNew[1] = __builtin_amdgcn_mfma_f32_32x32x16_f16(ka, qa[1][0], fz16, 0, 0, 0);
      } else {
        sNew[0] = __builtin_amdgcn_mfma_f32_32x32x16_f16(ka, qa[0][ks], sNew[0], 0, 0, 0);
        sNew[1] = __builtin_amdgcn_mfma_f32_32x32x16_f16(ka, qa[1][ks], sNew[1], 0, 0, 0);
      }
    }
  };

  // exp+pack one 8-value chunk of sOld -> pa[qm][ksb]
  auto chunk = [&](floatx16 (&sOld)[2], int qm, int ksb, uint4v (&pa)[2][2]) {
    float e[8];
    float ps = 0.f;
#pragma unroll
    for (int j = 0; j < 8; ++j) {
      e[j] = __builtin_amdgcn_exp2f(sOld[qm][8 * ksb + j]);
      ps += e[j];
    }
    lf[qm] += ps;
    uint x0 = pkrtz(e[0], e[1]), x1 = pkrtz(e[2], e[3]);
    uint y0 = pkrtz(e[4], e[5]), y1 = pkrtz(e[6], e[7]);
    pl32swap(x0, y0);
    pl32swap(x1, y1);
    pa[qm][ksb] = (uint4v){x0, x1, y0, y1};
  };

  // PV: acc += P(pa) . V[slotPV]
  auto pv = [&](int slotPV, uint4v (&pa)[2][2]) {
    const half_t* vt = vb_lds + slotPV * 4096;
    __builtin_amdgcn_s_setprio(1);
#pragma unroll
    for (int dn = 0; dn < 2; ++dn)
#pragma unroll
      for (int ks = 0; ks < 2; ++ks) {
        int byte = ((dn * 32 + lo) << 7) + ((kw * 32 + ks * 16 + h * 8) << 1);
        half8 vb = *(const half8*)&vt[swz128(byte) >> 1];
#pragma unroll
        for (int qm = 0; qm < 2; ++qm)
          acc[qm][dn] =
              __builtin_amdgcn_mfma_f32_32x32x16_f16(as_h8(pa[qm][ks]), vb, acc[qm][dn], 0, 0, 0);
      }
    __builtin_amdgcn_s_setprio(0);
  };

  // full round: QK(slotQK)->sNew interleaved with exp+pack(sOld), then PV
  auto full_round = [&](int slotQK, int slotPV, floatx16 (&sOld)[2], floatx16 (&sNew)[2]) {
    const half_t* kt = kb_lds + slotQK * 4096;
    uint4v pa[2][2];
#pragma unroll
    for (int ks = 0; ks < 4; ++ks) {
      int byte = ((kw * 32 + lo) << 7) + (ks << 5) + (h << 4);
      half8 ka = *(const half8*)&kt[swz128(byte) >> 1];
      if (ks == 0) {
        sNew[0] = __builtin_amdgcn_mfma_f32_32x32x16_f16(ka, qa[0][0], fz16, 0, 0, 0);
        sNew[1] = __builtin_amdgcn_mfma_f32_32x32x16_f16(ka, qa[1][0], fz16, 0, 0, 0);
      } else {
        sNew[0] = __builtin_amdgcn_mfma_f32_32x32x16_f16(ka, qa[0][ks], sNew[0], 0, 0, 0);
        sNew[1] = __builtin_amdgcn_mfma_f32_32x32x16_f16(ka, qa[1][ks], sNew[1], 0, 0, 0);
      }
      // independent VALU for the MFMA shadow: finish one 8-chunk of prev tile
      chunk(sOld, ks >> 1, ks & 1, pa);
    }
    pv(slotPV, pa);
  };

  floatx16 sA[2], sB[2];

  // prologue: 3 tiles in flight
  stage(0, 0);
  stage(1, 1);
  stage(2, 2);

  // round 0: QK(0) -> sA
  WAITB(8)
  stage(3, 3);
  qk_only(0, sA);

  // rounds 1..60 in ping-pong pairs; round r: stage(r+3), QK(r), finish(r-1)
  int sStage = 4, sQK = 1, sPV = 0;
  for (int r = 1; r <= 60; r += 2) {
    WAITB(8)
    stage(sStage, r + 3);
    full_round(sQK, sPV, sA, sB);  // QK(r)->sB, finish(r-1) from sA
    sStage = (sStage == 4) ? 0 : sStage + 1;
    sQK = (sQK == 4) ? 0 : sQK + 1;
    sPV = (sPV == 4) ? 0 : sPV + 1;

    WAITB(8)
    stage(sStage, r + 4);
    full_round(sQK, sPV, sB, sA);  // QK(r+1)->sA, finish(r) from sB
    sStage = (sStage == 4) ? 0 : sStage + 1;
    sQK = (sQK == 4) ? 0 : sQK + 1;
    sPV = (sPV == 4) ? 0 : sPV + 1;
  }
  // rounds 61..63 (no staging; tiles 61,62,63 outstanding -> 8/4/0)
  WAITB(8)
  full_round(sQK, sPV, sA, sB);  // QK(61)->sB, finish(60) from sA
  sQK = (sQK == 4) ? 0 : sQK + 1;
  sPV = (sPV == 4) ? 0 : sPV + 1;
  WAITB(4)
  full_round(sQK, sPV, sB, sA);  // QK(62)->sA, finish(61) from sB
  sQK = (sQK == 4) ? 0 : sQK + 1;
  sPV = (sPV == 4) ? 0 : sPV + 1;
  WAITB(0)
  full_round(sQK, sPV, sA, sB);  // QK(63)->sB, finish(62) from sA
  sPV = (sPV == 4) ? 0 : sPV + 1;

  // post: finish(63) from sB, PV slot = 63 % 5 = 3
  {
    uint4v pa[2][2];
#pragma unroll
    for (int ks = 0; ks < 4; ++ks) chunk(sB, ks >> 1, ks & 1, pa);
    pv(sPV, pa);
  }

  // ---- cross-wave (k-half) reduction + normalize + store (v6 verbatim) ----
#pragma unroll
  for (int qm = 0; qm < 2; ++qm) lf[qm] += __shfl_xor(lf[qm], 32);

  float* red = (float*)smem;             // 32 KB: [qw][qm][dn][r][lane]
  float* redl = (float*)(smem + 32768);  // 1 KB: [qw][qm][lane]

  __syncthreads();
  if (kw == 1) {
#pragma unroll
    for (int qm = 0; qm < 2; ++qm) {
      redl[(qw * 2 + qm) * 64 + l] = lf[qm];
#pragma unroll
      for (int dn = 0; dn < 2; ++dn)
#pragma unroll
        for (int r = 0; r < 16; ++r)
          red[((((qw * 2 + qm) * 2 + dn) * 16) + r) * 64 + l] = acc[qm][dn][r];
    }
  }
  __syncthreads();
  if (kw == 0) {
    float inv[2];
#pragma unroll
    for (int qm = 0; qm < 2; ++qm)
      inv[qm] = 1.0f / (lf[qm] + redl[(qw * 2 + qm) * 64 + l]);
#pragma unroll
    for (int qm = 0; qm < 2; ++qm)
#pragma unroll
      for (int r = 0; r < 16; ++r) {
        int ro = (r & 3) + 8 * (r >> 2) + 4 * h;
        float iv = __shfl(inv[qm], ro);
#pragma unroll
        for (int dn = 0; dn < 2; ++dn) {
          float o = (acc[qm][dn][r] + red[((((qw * 2 + qm) * 2 + dn) * 16) + r) * 64 + l]) * iv;
          Ob[(size_t)(qm * 32 + ro) * 512 + dn * 32 + lo] = (half_t)o;
        }
      }
  }
}

extern "C" void kernel_launch(void* const* d_in, const int* in_sizes, int n_in,
                              void* d_out, int out_size, void* d_ws, size_t ws_size,
                              hipStream_t stream) {
  const float* X  = (const float*)d_in[0];
  const float* Wq = (const float*)d_in[1];
  const float* Wk = (const float*)d_in[2];
  const float* Wv = (const float*)d_in[3];
  const float* Wo = (const float*)d_in[4];
  const float* bo = (const float*)d_in[5];
  float* out = (float*)d_out;

  char* ws = (char*)d_ws;
  half_t* X16  = (half_t*)(ws);                 // 8 MB
  half_t* W16  = (half_t*)(ws + 8388608);       // 2 MB (Wq|Wk|Wv|Wo)
  half_t* Q16  = (half_t*)(ws + 10485760);      // 8 MB
  half_t* K16  = (half_t*)(ws + 18874368);      // 8 MB
  half_t* VtW  = (half_t*)(ws + 27262976);      // 8 MB  [B][H][64][4096]
  half_t* O16  = (half_t*)(ws + 35651584);      // 8 MB
  half_t* Wq16 = W16;
  half_t* Wk16 = W16 + 262144;
  half_t* Wv16 = W16 + 524288;
  half_t* Wo16 = W16 + 786432;

  cvt_kernel<<<2560, 256, 0, stream>>>(X, Wq, Wk, Wv, Wo, X16, W16);
  gemm01_kernel<<<768, 256, 0, stream>>>(X16, Wq16, Wk16, Wv16, Q16, K16, VtW);
  attn_kernel<<<512, 256, 0, stream>>>(Q16, K16, VtW, O16);
  gemm2_kernel<<<256, 256, 0, stream>>>(O16, Wo16, out, bo);
}

// Round 14
// 117.262 us; speedup vs baseline: 1.1883x; 1.0059x over previous
//
#include <hip/hip_runtime.h>
#include <stdint.h>

typedef _Float16 half_t;
typedef _Float16 half8 __attribute__((ext_vector_type(8)));
typedef __fp16 fp16x2 __attribute__((ext_vector_type(2)));
typedef float floatx4 __attribute__((ext_vector_type(4)));
typedef float floatx16 __attribute__((ext_vector_type(16)));
typedef unsigned int uint;
typedef unsigned int uint4v __attribute__((ext_vector_type(4)));

#define LOG2E 1.4426950408889634f

__device__ __forceinline__ void gload_lds16(const void* g, void* l) {
  __builtin_amdgcn_global_load_lds(
      (__attribute__((address_space(1))) void*)(uintptr_t)g,
      (__attribute__((address_space(3))) void*)(uintptr_t)l, 16, 0, 0);
}

// involution swizzles: XOR byte bits 4..6 with low row bits (keeps 16B alignment)
__device__ __forceinline__ int swz64(int b)  { return b ^ (((b >> 7) & 3) << 4); }   // 64B rows
__device__ __forceinline__ int swz128(int b) { return b ^ (((b >> 7) & 7) << 4); }   // 128B rows

__device__ __forceinline__ uint pkrtz(float a, float b) {
  union { fp16x2 h; uint u; } cv;
  cv.h = __builtin_amdgcn_cvt_pkrtz(a, b);
  return cv.u;
}
__device__ __forceinline__ void pl32swap(uint &x, uint &y) {
  asm("v_permlane32_swap_b32 %0, %1" : "+v"(x), "+v"(y));
}
__device__ __forceinline__ half8 as_h8(uint4v v) {
  union { uint4v u; half8 h; } c; c.u = v; return c.h;
}

#define WAITB(N)                                          \
  asm volatile("s_waitcnt vmcnt(" #N ")" ::: "memory");   \
  __builtin_amdgcn_s_barrier();                           \
  __builtin_amdgcn_sched_barrier(0);

// ---------------- fused fp32 -> fp16 converts (X and all W) ----------------
__global__ void cvt_kernel(const float* __restrict__ X, const float* __restrict__ Wq,
                           const float* __restrict__ Wk, const float* __restrict__ Wv,
                           const float* __restrict__ Wo, half_t* __restrict__ X16,
                           half_t* __restrict__ W16) {
  int gid = blockIdx.x;
  if (gid < 2048) {
    int i = (gid * 256 + threadIdx.x) * 8;
    float4 u = *(const float4*)(X + i);
    float4 v = *(const float4*)(X + i + 4);
    half8 o = {(half_t)u.x, (half_t)u.y, (half_t)u.z, (half_t)u.w,
               (half_t)v.x, (half_t)v.y, (half_t)v.z, (half_t)v.w};
    *(half8*)(X16 + i) = o;
  } else {
    int i = (gid - 2048) * 256 + threadIdx.x;
    int widx = i >> 15;
    int j = (i & 32767) * 8;
    const float* src = (widx == 0) ? Wq : (widx == 1) ? Wk : (widx == 2) ? Wv : Wo;
    float sc = (widx == 0) ? 0.125f * LOG2E : 1.0f;  // fold 1/sqrt(64) AND log2(e) into Wq
    float4 u = *(const float4*)(src + j);
    float4 v = *(const float4*)(src + j + 4);
    half8 o = {(half_t)(u.x * sc), (half_t)(u.y * sc), (half_t)(u.z * sc), (half_t)(u.w * sc),
               (half_t)(v.x * sc), (half_t)(v.y * sc), (half_t)(v.z * sc), (half_t)(v.w * sc)};
    *(half8*)(W16 + widx * 262144 + j) = o;
  }
}

// ---------------- NT fp16 GEMM body, 128x128 tile, BK=32, K=512 ----------------
// T3/T4 ring schedule (verified r12/r13). RING=3: 48KB LDS -> 3 blocks/CU,
// 2-deep prefetch. RING=4: 64KB, 3-deep (for grid-limited launches).
// Same kt order either way -> bit-identical results.
template <int MODE, int RING>
__device__ __forceinline__ void gemm_body(
    int bidx, const half_t* __restrict__ A, const half_t* __restrict__ B0,
    const half_t* __restrict__ B1, half_t* __restrict__ outh,
    half_t* __restrict__ outh2, float* __restrict__ outf,
    const float* __restrict__ bias, half_t (*As)[4096], half_t (*Bs)[4096]) {
  const int tid = threadIdx.x;
  const int w = tid >> 6, l = tid & 63, g = l >> 4, c = l & 15;
  const int wr = w >> 1, wc = w & 1;

  int rt, ct;
  const half_t *Ab, *Bb;
  if (MODE == 0) {
    rt = bidx >> 3; ct = bidx & 7;
    Ab = A + (size_t)rt * 128 * 512;
    Bb = ((ct < 4) ? B0 : B1) + (size_t)(ct & 3) * 128 * 512;
  } else if (MODE == 1) {
    rt = bidx >> 6; ct = bidx & 63;
    Ab = A + (size_t)rt * 128 * 512;
    Bb = B0 + (size_t)ct * 128 * 512;
  } else {
    rt = bidx >> 2; ct = bidx & 3;
    Ab = A + (size_t)rt * 128 * 512;
    Bb = B0 + (size_t)ct * 128 * 512;
  }

  const floatx4 fzero = {0.f, 0.f, 0.f, 0.f};
  floatx4 acc[4][4];
#pragma unroll
  for (int m = 0; m < 4; ++m)
#pragma unroll
    for (int n = 0; n < 4; ++n) acc[m][n] = fzero;

  auto stage = [&](int slot, int kt) {
#pragma unroll
    for (int i = 0; i < 2; ++i) {
      int rel = i * 4096 + tid * 16;
      int lg = swz64(rel);
      int row = lg >> 6, inner = (lg & 63) >> 1;
      gload_lds16(Ab + (size_t)row * 512 + kt * 32 + inner, As[slot] + (rel >> 1));
      gload_lds16(Bb + (size_t)row * 512 + kt * 32 + inner, Bs[slot] + (rel >> 1));
    }
  };

  auto compute = [&](int slot) {
    half8 a[4], b[4];
#pragma unroll
    for (int m = 0; m < 4; ++m)
      a[m] = *(const half8*)&As[slot][swz64(((wr * 64 + m * 16 + c) << 6) + (g << 4)) >> 1];
#pragma unroll
    for (int n = 0; n < 4; ++n)
      b[n] = *(const half8*)&Bs[slot][swz64(((wc * 64 + n * 16 + c) << 6) + (g << 4)) >> 1];
#pragma unroll
    for (int m = 0; m < 4; ++m)
#pragma unroll
      for (int n = 0; n < 4; ++n)
        acc[m][n] = __builtin_amdgcn_mfma_f32_16x16x32_f16(a[m], b[n], acc[m][n], 0, 0, 0);
  };

  if constexpr (RING == 3) {
    // 2 tiles in flight (8 outstanding gload_lds/thread); tile t -> slot t%3
    stage(0, 0);
    stage(1, 1);
    for (int kt = 0; kt < 14; ++kt) {
      WAITB(4)                      // drains tile kt (kt, kt+1 outstanding)
      stage((kt + 2) % 3, kt + 2);  // overwrites slot read in round kt-1
      compute(kt % 3);
    }
    WAITB(4)
    compute(14 % 3);
    WAITB(0)
    compute(15 % 3);
  } else {
    // 3 tiles in flight (12 outstanding); tile t -> slot t%4
    stage(0, 0);
    stage(1, 1);
    stage(2, 2);
    for (int kt = 0; kt < 13; ++kt) {
      WAITB(8)
      stage((kt + 3) & 3, kt + 3);
      compute(kt & 3);
    }
    WAITB(8)
    compute(1);
    WAITB(4)
    compute(2);
    WAITB(0)
    compute(3);
  }

  const int r0 = wr * 64, c0 = wc * 64;
  if (MODE == 0) {
    half_t* O = ((ct < 4) ? outh : outh2) + (size_t)rt * 128 * 512 + (size_t)(ct & 3) * 128;
#pragma unroll
    for (int m = 0; m < 4; ++m)
#pragma unroll
      for (int j = 0; j < 4; ++j)
#pragma unroll
        for (int n = 0; n < 4; ++n)
          O[(size_t)(r0 + m * 16 + g * 4 + j) * 512 + c0 + n * 16 + c] = (half_t)acc[m][n][j];
  } else if (MODE == 1) {
    half_t* O = outh + (size_t)(ct >> 5) * 2097152 + (size_t)(ct & 31) * 128;
#pragma unroll
    for (int m = 0; m < 4; ++m)
#pragma unroll
      for (int j = 0; j < 4; ++j)
#pragma unroll
        for (int n = 0; n < 4; ++n)
          O[(size_t)(rt * 128 + r0 + m * 16 + g * 4 + j) * 4096 + c0 + n * 16 + c] =
              (half_t)acc[m][n][j];
  } else {
    float* O = outf + (size_t)rt * 128 * 512 + ct * 128;
    float bv[4];
#pragma unroll
    for (int n = 0; n < 4; ++n) bv[n] = bias[ct * 128 + c0 + n * 16 + c];
#pragma unroll
    for (int m = 0; m < 4; ++m)
#pragma unroll
      for (int j = 0; j < 4; ++j)
#pragma unroll
        for (int n = 0; n < 4; ++n)
          O[(size_t)(r0 + m * 16 + g * 4 + j) * 512 + c0 + n * 16 + c] = acc[m][n][j] + bv[n];
  }
}

// fused Q/K-proj (blocks 0..511, MODE 0) + V^T-proj (512..767, MODE 1);
// per-mode bijective XCD swizzle. RING=3 (48KB LDS) -> all 768 blocks resident.
__global__ __launch_bounds__(256) void gemm01_kernel(
    const half_t* __restrict__ X16, const half_t* __restrict__ Wq16,
    const half_t* __restrict__ Wk16, const half_t* __restrict__ Wv16,
    half_t* __restrict__ Q16, half_t* __restrict__ K16, half_t* __restrict__ VtW) {
  __shared__ __attribute__((aligned(16))) half_t As[3][4096];
  __shared__ __attribute__((aligned(16))) half_t Bs[3][4096];
  int x = blockIdx.x;
  if (x < 512) {
    int bid = (x & 7) * 64 + (x >> 3);
    gemm_body<0, 3>(bid, X16, Wq16, Wk16, Q16, K16, nullptr, nullptr, As, Bs);
  } else {
    int lb = x - 512;
    int bid = (lb & 7) * 32 + (lb >> 3);
    gemm_body<1, 3>(bid, Wv16, X16, nullptr, VtW, nullptr, nullptr, nullptr, As, Bs);
  }
}

// O-projection (+bias), 256 blocks (1/CU, grid-limited) -> keep RING=4 depth.
__global__ __launch_bounds__(256) void gemm2_kernel(
    const half_t* __restrict__ O16, const half_t* __restrict__ Wo16,
    float* __restrict__ out, const float* __restrict__ bias) {
  __shared__ __attribute__((aligned(16))) half_t As[4][4096];
  __shared__ __attribute__((aligned(16))) half_t Bs[4][4096];
  int x = blockIdx.x;
  int bid = (x & 7) * 32 + (x >> 3);
  gemm_body<2, 4>(bid, O16, Wo16, nullptr, nullptr, nullptr, out, bias, As, Bs);
}

// ---------------- flash attention v10 (verified, kept byte-for-byte) ----------------
__global__ __launch_bounds__(256, 2) void attn_kernel(
    const half_t* __restrict__ Q16, const half_t* __restrict__ K16,
    const half_t* __restrict__ Vt, half_t* __restrict__ O16) {
  // [0,40K): K slots [5][64 key][64 d]; [40K,80K): V slots [5][64 d][64 key].
  // Epilogue: red reuses [0,32K), redl [32K,33K).
  __shared__ __attribute__((aligned(16))) char smem[81920];
  half_t* kb_lds = (half_t*)smem;
  half_t* vb_lds = (half_t*)(smem + 40960);

  const int tid = threadIdx.x;
  const int w = tid >> 6, l = tid & 63, lo = l & 31, h = l >> 5;
  const int kw = w >> 1, qw = w & 1;
  // bijective XCD swizzle: 512 blocks -> chunks of 64 per XCD
  const int bid = (blockIdx.x & 7) * 64 + (blockIdx.x >> 3);
  const int bh = bid >> 5, qt = bid & 31;
  const int b = bh >> 3, hh = bh & 7;

  const half_t* Qb = Q16 + (size_t)(b * 4096 + qt * 128 + qw * 64) * 512 + hh * 64;
  const half_t* Kb = K16 + (size_t)b * 4096 * 512 + hh * 64;
  const half_t* Vb = Vt + (size_t)bh * 262144;  // [64 d][4096 s]
  half_t* Ob = O16 + (size_t)(b * 4096 + qt * 128 + qw * 64) * 512 + hh * 64;

  // Q fragments (B-operand): row q = qm*32+lo, elems d = ks*16 + h*8 .. +7
  half8 qa[2][4];
#pragma unroll
  for (int qm = 0; qm < 2; ++qm)
#pragma unroll
    for (int ks = 0; ks < 4; ++ks)
      qa[qm][ks] = *(const half8*)(Qb + (size_t)(qm * 32 + lo) * 512 + ks * 16 + h * 8);

  floatx16 acc[2][2];
#pragma unroll
  for (int qm = 0; qm < 2; ++qm)
#pragma unroll
    for (int dn = 0; dn < 2; ++dn)
#pragma unroll
      for (int r = 0; r < 16; ++r) acc[qm][dn][r] = 0.f;
  float lf[2] = {0.f, 0.f};

  floatx16 fz16;
#pragma unroll
  for (int r = 0; r < 16; ++r) fz16[r] = 0.f;

  // stage K/V tile t (64 keys) into slot (8KB each side); 4 gload per thread
  auto stage = [&](int slot, int t) {
#pragma unroll
    for (int i = 0; i < 2; ++i) {
      int rel = i * 4096 + tid * 16;
      int lg = swz128(rel);
      int row = lg >> 7, inner = (lg & 127) >> 1;
      gload_lds16(Kb + (size_t)(t * 64 + row) * 512 + inner,
                  kb_lds + slot * 4096 + (rel >> 1));
      gload_lds16(Vb + (size_t)row * 4096 + t * 64 + inner,
                  vb_lds + slot * 4096 + (rel >> 1));
    }
  };

  // QK only (round 0): sNew = K[slotQK] . Q^T
  auto qk_only = [&](int slotQK, floatx16 (&sNew)[2]) {
    const half_t* kt = kb_lds + slotQK * 4096;
#pragma unroll
    for (int ks = 0; ks < 4; ++ks) {
      int byte = ((kw * 32 + lo) << 7) + (ks << 5) + (h << 4);
      half8 ka = *(const half8*)&kt[swz128(byte) >> 1];
      if (ks == 0) {
        sNew[0] = __builtin_amdgcn_mfma_f32_32x32x16_f16(ka, qa[0][0], fz16, 0, 0, 0);
        sNew[1] = __builtin_amdgcn_mfma_f32_32x32x16_f16(ka, qa[1][0], fz16, 0, 0, 0);
      } else {
        sNew[0] = __builtin_amdgcn_mfma_f32_32x32x16_f16(ka, qa[0][ks], sNew[0], 0, 0, 0);
        sNew[1] = __builtin_amdgcn_mfma_f32_32x32x16_f16(ka, qa[1][ks], sNew[1], 0, 0, 0);
      }
    }
  };

  // exp+pack one 8-value chunk of sOld -> pa[qm][ksb]
  auto chunk = [&](floatx16 (&sOld)[2], int qm, int ksb, uint4v (&pa)[2][2]) {
    float e[8];
    float ps = 0.f;
#pragma unroll
    for (int j = 0; j < 8; ++j) {
      e[j] = __builtin_amdgcn_exp2f(sOld[qm][8 * ksb + j]);
      ps += e[j];
    }
    lf[qm] += ps;
    uint x0 = pkrtz(e[0], e[1]), x1 = pkrtz(e[2], e[3]);
    uint y0 = pkrtz(e[4], e[5]), y1 = pkrtz(e[6], e[7]);
    pl32swap(x0, y0);
    pl32swap(x1, y1);
    pa[qm][ksb] = (uint4v){x0, x1, y0, y1};
  };

  // PV: acc += P(pa) . V[slotPV]
  auto pv = [&](int slotPV, uint4v (&pa)[2][2]) {
    const half_t* vt = vb_lds + slotPV * 4096;
    __builtin_amdgcn_s_setprio(1);
#pragma unroll
    for (int dn = 0; dn < 2; ++dn)
#pragma unroll
      for (int ks = 0; ks < 2; ++ks) {
        int byte = ((dn * 32 + lo) << 7) + ((kw * 32 + ks * 16 + h * 8) << 1);
        half8 vb = *(const half8*)&vt[swz128(byte) >> 1];
#pragma unroll
        for (int qm = 0; qm < 2; ++qm)
          acc[qm][dn] =
              __builtin_amdgcn_mfma_f32_32x32x16_f16(as_h8(pa[qm][ks]), vb, acc[qm][dn], 0, 0, 0);
      }
    __builtin_amdgcn_s_setprio(0);
  };

  // full round: QK(slotQK)->sNew interleaved with exp+pack(sOld), then PV
  auto full_round = [&](int slotQK, int slotPV, floatx16 (&sOld)[2], floatx16 (&sNew)[2]) {
    const half_t* kt = kb_lds + slotQK * 4096;
    uint4v pa[2][2];
#pragma unroll
    for (int ks = 0; ks < 4; ++ks) {
      int byte = ((kw * 32 + lo) << 7) + (ks << 5) + (h << 4);
      half8 ka = *(const half8*)&kt[swz128(byte) >> 1];
      if (ks == 0) {
        sNew[0] = __builtin_amdgcn_mfma_f32_32x32x16_f16(ka, qa[0][0], fz16, 0, 0, 0);
        sNew[1] = __builtin_amdgcn_mfma_f32_32x32x16_f16(ka, qa[1][0], fz16, 0, 0, 0);
      } else {
        sNew[0] = __builtin_amdgcn_mfma_f32_32x32x16_f16(ka, qa[0][ks], sNew[0], 0, 0, 0);
        sNew[1] = __builtin_amdgcn_mfma_f32_32x32x16_f16(ka, qa[1][ks], sNew[1], 0, 0, 0);
      }
      // independent VALU for the MFMA shadow: finish one 8-chunk of prev tile
      chunk(sOld, ks >> 1, ks & 1, pa);
    }
    pv(slotPV, pa);
  };

  floatx16 sA[2], sB[2];

  // prologue: 3 tiles in flight
  stage(0, 0);
  stage(1, 1);
  stage(2, 2);

  // round 0: QK(0) -> sA
  WAITB(8)
  stage(3, 3);
  qk_only(0, sA);

  // rounds 1..60 in ping-pong pairs; round r: stage(r+3), QK(r), finish(r-1)
  int sStage = 4, sQK = 1, sPV = 0;
  for (int r = 1; r <= 60; r += 2) {
    WAITB(8)
    stage(sStage, r + 3);
    full_round(sQK, sPV, sA, sB);  // QK(r)->sB, finish(r-1) from sA
    sStage = (sStage == 4) ? 0 : sStage + 1;
    sQK = (sQK == 4) ? 0 : sQK + 1;
    sPV = (sPV == 4) ? 0 : sPV + 1;

    WAITB(8)
    stage(sStage, r + 4);
    full_round(sQK, sPV, sB, sA);  // QK(r+1)->sA, finish(r) from sB
    sStage = (sStage == 4) ? 0 : sStage + 1;
    sQK = (sQK == 4) ? 0 : sQK + 1;
    sPV = (sPV == 4) ? 0 : sPV + 1;
  }
  // rounds 61..63 (no staging; tiles 61,62,63 outstanding -> 8/4/0)
  WAITB(8)
  full_round(sQK, sPV, sA, sB);  // QK(61)->sB, finish(60) from sA
  sQK = (sQK == 4) ? 0 : sQK + 1;
  sPV = (sPV == 4) ? 0 : sPV + 1;
  WAITB(4)
  full_round(sQK, sPV, sB, sA);  // QK(62)->sA, finish(61) from sB
  sQK = (sQK == 4) ? 0 : sQK + 1;
  sPV = (sPV == 4) ? 0 : sPV + 1;
  WAITB(0)
  full_round(sQK, sPV, sA, sB);  // QK(63)->sB, finish(62) from sA
  sPV = (sPV == 4) ? 0 : sPV + 1;

  // post: finish(63) from sB, PV slot = 63 % 5 = 3
  {
    uint4v pa[2][2];
#pragma unroll
    for (int ks = 0; ks < 4; ++ks) chunk(sB, ks >> 1, ks & 1, pa);
    pv(sPV, pa);
  }

  // ---- cross-wave (k-half) reduction + normalize + store (v6 verbatim) ----
#pragma unroll
  for (int qm = 0; qm < 2; ++qm) lf[qm] += __shfl_xor(lf[qm], 32);

  float* red = (float*)smem;             // 32 KB: [qw][qm][dn][r][lane]
  float* redl = (float*)(smem + 32768);  // 1 KB: [qw][qm][lane]

  __syncthreads();
  if (kw == 1) {
#pragma unroll
    for (int qm = 0; qm < 2; ++qm) {
      redl[(qw * 2 + qm) * 64 + l] = lf[qm];
#pragma unroll
      for (int dn = 0; dn < 2; ++dn)
#pragma unroll
        for (int r = 0; r < 16; ++r)
          red[((((qw * 2 + qm) * 2 + dn) * 16) + r) * 64 + l] = acc[qm][dn][r];
    }
  }
  __syncthreads();
  if (kw == 0) {
    float inv[2];
#pragma unroll
    for (int qm = 0; qm < 2; ++qm)
      inv[qm] = 1.0f / (lf[qm] + redl[(qw * 2 + qm) * 64 + l]);
#pragma unroll
    for (int qm = 0; qm < 2; ++qm)
#pragma unroll
      for (int r = 0; r < 16; ++r) {
        int ro = (r & 3) + 8 * (r >> 2) + 4 * h;
        float iv = __shfl(inv[qm], ro);
#pragma unroll
        for (int dn = 0; dn < 2; ++dn) {
          float o = (acc[qm][dn][r] + red[((((qw * 2 + qm) * 2 + dn) * 16) + r) * 64 + l]) * iv;
          Ob[(size_t)(qm * 32 + ro) * 512 + dn * 32 + lo] = (half_t)o;
        }
      }
  }
}

extern "C" void kernel_launch(void* const* d_in, const int* in_sizes, int n_in,
                              void* d_out, int out_size, void* d_ws, size_t ws_size,
                              hipStream_t stream) {
  const float* X  = (const float*)d_in[0];
  const float* Wq = (const float*)d_in[1];
  const float* Wk = (const float*)d_in[2];
  const float* Wv = (const float*)d_in[3];
  const float* Wo = (const float*)d_in[4];
  const float* bo = (const float*)d_in[5];
  float* out = (float*)d_out;

  char* ws = (char*)d_ws;
  half_t* X16  = (half_t*)(ws);                 // 8 MB
  half_t* W16  = (half_t*)(ws + 8388608);       // 2 MB (Wq|Wk|Wv|Wo)
  half_t* Q16  = (half_t*)(ws + 10485760);      // 8 MB
  half_t* K16  = (half_t*)(ws + 18874368);      // 8 MB
  half_t* VtW  = (half_t*)(ws + 27262976);      // 8 MB  [B][H][64][4096]
  half_t* O16  = (half_t*)(ws + 35651584);      // 8 MB
  half_t* Wq16 = W16;
  half_t* Wk16 = W16 + 262144;
  half_t* Wv16 = W16 + 524288;
  half_t* Wo16 = W16 + 786432;

  cvt_kernel<<<2560, 256, 0, stream>>>(X, Wq, Wk, Wv, Wo, X16, W16);
  gemm01_kernel<<<768, 256, 0, stream>>>(X16, Wq16, Wk16, Wv16, Q16, K16, VtW);
  attn_kernel<<<512, 256, 0, stream>>>(Q16, K16, VtW, O16);
  gemm2_kernel<<<256, 256, 0, stream>>>(O16, Wo16, out, bo);
}